// Round 1
// 667.097 us; speedup vs baseline: 1.0717x; 1.0717x over previous
//
#include <hip/hip_runtime.h>

#define N 32768
#define F 768
#define C 64
#define P 8192
#define TAU 1e-3f

typedef __attribute__((ext_vector_type(8))) short short8;
typedef __attribute__((ext_vector_type(4))) float f32x4;

// ---------------- workspace layout (float offsets) ----------------
#define WS_CNT    0                        // cnT   fp32 [C][P] k-major (gather+recheck)
#define WS_CC     (WS_CNT + C*P)           // cc    [P]
#define WS_ZQT    (WS_CC + P)              // zqT   fp32 [C][N] k-major (loss+recheck)
#define WS_CODEST (WS_ZQT + C*N)           // codesT[C][N]
#define WS_IDX    (WS_CODEST + C*N)        // idx   [N] int
#define WS_QN     (WS_IDX + N)             // queue count (int)
#define WS_ACC    (WS_QN + 1)              // loss accumulator
#define WS_QLIST  (WS_ACC + 1)             // queue [N] int
#define WS_CNH    ((WS_QLIST + N + 3) & ~3)  // cn_hi bf16 [P][C] row-major
#define WS_CNL    (WS_CNH + (C*P)/2)       // cn_lo bf16 [P][C]
#define WS_ZQH    (WS_CNL + (C*P)/2)       // zq_hi bf16 [N][C] row-major
#define WS_ZQL    (WS_ZQH + (C*N)/2)       // zq_lo bf16 [N][C]
#define WS_D12    (WS_ZQL + (C*N)/2)       // float4 [2][N]: (d1, d2, i1_bits, pad)
// end = WS_D12 + 2*N*4 ≈ 7.68M floats ≈ 30.7 MB

#define OUT_LOSS_OFF (N*F)
#define OUT_IDX_OFF  (N*F + 1)

__device__ inline unsigned short f2bf(float x) {   // fp32 -> bf16 RNE
    union { float f; unsigned u; } v; v.f = x;
    unsigned r = v.u + 0x7fffu + ((v.u >> 16) & 1u);
    return (unsigned short)(r >> 16);
}
__device__ inline float bf2f(unsigned short b) {
    union { unsigned u; float f; } v; v.u = ((unsigned)b) << 16;
    return v.f;
}

// ---------------- K1: normalize codebook -> cnT [C][P], cc, cn_hi/lo [P][C] ----
__global__ __launch_bounds__(256) void k1_norm_codebook(
    const float* __restrict__ cb, float* __restrict__ cnT, float* __restrict__ cc,
    unsigned short* __restrict__ cnh, unsigned short* __restrict__ cnl) {
    int p = blockIdx.x * 256 + threadIdx.x;   // one thread per page
    const float4* cb4 = (const float4*)(cb + (size_t)p * C);
    float4 v[16];
    float ss = 0.f;
#pragma unroll
    for (int i = 0; i < 16; ++i) {
        v[i] = cb4[i];
        ss += v[i].x * v[i].x + v[i].y * v[i].y + v[i].z * v[i].z + v[i].w * v[i].w;
    }
    float nrm = sqrtf(ss);
    float s2 = 0.f;
    unsigned short hb[64], lb[64];
#pragma unroll
    for (int i = 0; i < 16; ++i) {
        float c4[4] = {v[i].x / nrm, v[i].y / nrm, v[i].z / nrm, v[i].w / nrm};
#pragma unroll
        for (int j = 0; j < 4; ++j) {
            cnT[(size_t)(i * 4 + j) * P + p] = c4[j];
            s2 += c4[j] * c4[j];
            unsigned short h = f2bf(c4[j]);
            hb[i * 4 + j] = h;
            lb[i * 4 + j] = f2bf(c4[j] - bf2f(h));
        }
    }
    cc[p] = s2;
#pragma unroll
    for (int i = 0; i < 8; ++i) {
        uint4 hv, lv;
        hv.x = (unsigned)hb[i*8+0] | ((unsigned)hb[i*8+1] << 16);
        hv.y = (unsigned)hb[i*8+2] | ((unsigned)hb[i*8+3] << 16);
        hv.z = (unsigned)hb[i*8+4] | ((unsigned)hb[i*8+5] << 16);
        hv.w = (unsigned)hb[i*8+6] | ((unsigned)hb[i*8+7] << 16);
        lv.x = (unsigned)lb[i*8+0] | ((unsigned)lb[i*8+1] << 16);
        lv.y = (unsigned)lb[i*8+2] | ((unsigned)lb[i*8+3] << 16);
        lv.z = (unsigned)lb[i*8+4] | ((unsigned)lb[i*8+5] << 16);
        lv.w = (unsigned)lb[i*8+6] | ((unsigned)lb[i*8+7] << 16);
        *(uint4*)&cnh[(size_t)p * 64 + i * 8] = hv;
        *(uint4*)&cnl[(size_t)p * 64 + i * 8] = lv;
    }
}

// ---------------- K2: zq = normalize(z @ w_in^T + b_in) -> zqT, zq_hi/lo ----
__global__ __launch_bounds__(256) void k2_project(
    const float* __restrict__ z, const float* __restrict__ w_in, const float* __restrict__ b_in,
    float* __restrict__ zqT, unsigned short* __restrict__ zqh, unsigned short* __restrict__ zql) {
    __shared__ float zrow[128 * 33];
    __shared__ float wrow[64 * 32];
    __shared__ float red[128 * 9];
    int tid = threadIdx.x;
    int tr = tid & 31;        // row group: 4 rows each -> 128 rows
    int tc = tid >> 5;        // code group: 8 codes each -> 64 codes
    int rb = blockIdx.x * 128;

    float y[4][8];
#pragma unroll
    for (int i = 0; i < 4; ++i)
#pragma unroll
        for (int j = 0; j < 8; ++j) y[i][j] = 0.f;

    for (int kt = 0; kt < F; kt += 32) {
        __syncthreads();
        for (int i = tid; i < 128 * 32; i += 256) {
            int r = i >> 5, k = i & 31;
            zrow[r * 33 + k] = z[(size_t)(rb + r) * F + kt + k];
        }
        for (int i = tid; i < 64 * 32; i += 256) {
            int c = i >> 5, k = i & 31;
            wrow[c * 32 + k] = w_in[(size_t)c * F + kt + k];
        }
        __syncthreads();
#pragma unroll
        for (int k4 = 0; k4 < 8; ++k4) {
            float zs[4][4];
#pragma unroll
            for (int i = 0; i < 4; ++i)
#pragma unroll
                for (int kk = 0; kk < 4; ++kk)
                    zs[i][kk] = zrow[(tr * 4 + i) * 33 + k4 * 4 + kk];
#pragma unroll
            for (int j = 0; j < 8; ++j) {
                float4 wv = *(const float4*)&wrow[(tc * 8 + j) * 32 + k4 * 4];
#pragma unroll
                for (int i = 0; i < 4; ++i)
                    y[i][j] = fmaf(zs[i][3], wv.w,
                              fmaf(zs[i][2], wv.z,
                              fmaf(zs[i][1], wv.y,
                              fmaf(zs[i][0], wv.x, y[i][j]))));
            }
        }
    }
#pragma unroll
    for (int j = 0; j < 8; ++j) {
        float b = b_in[tc * 8 + j];
#pragma unroll
        for (int i = 0; i < 4; ++i) y[i][j] += b;
    }
    __syncthreads();
#pragma unroll
    for (int i = 0; i < 4; ++i) {
        float s = 0.f;
#pragma unroll
        for (int j = 0; j < 8; ++j) s += y[i][j] * y[i][j];
        red[(tr * 4 + i) * 9 + tc] = s;
    }
    __syncthreads();
    float nrm[4];
#pragma unroll
    for (int i = 0; i < 4; ++i) {
        float t = 0.f;
#pragma unroll
        for (int t8 = 0; t8 < 8; ++t8) t += red[(tr * 4 + i) * 9 + t8];
        nrm[i] = sqrtf(t);
    }
    float q[4][8];
#pragma unroll
    for (int i = 0; i < 4; ++i)
#pragma unroll
        for (int j = 0; j < 8; ++j) q[i][j] = y[i][j] / nrm[i];
    // store transposed fp32: zqT[c][rb + tr*4 .. +3]
#pragma unroll
    for (int j = 0; j < 8; ++j) {
        int c = tc * 8 + j;
        float4 o = make_float4(q[0][j], q[1][j], q[2][j], q[3][j]);
        *(float4*)&zqT[(size_t)c * N + rb + tr * 4] = o;
    }
    // store row-major bf16 hi/lo: zqh/zql[row][64]
#pragma unroll
    for (int i = 0; i < 4; ++i) {
        unsigned short h[8], l[8];
#pragma unroll
        for (int j = 0; j < 8; ++j) {
            h[j] = f2bf(q[i][j]);
            l[j] = f2bf(q[i][j] - bf2f(h[j]));
        }
        uint4 hv, lv;
        hv.x = (unsigned)h[0] | ((unsigned)h[1] << 16);
        hv.y = (unsigned)h[2] | ((unsigned)h[3] << 16);
        hv.z = (unsigned)h[4] | ((unsigned)h[5] << 16);
        hv.w = (unsigned)h[6] | ((unsigned)h[7] << 16);
        lv.x = (unsigned)l[0] | ((unsigned)l[1] << 16);
        lv.y = (unsigned)l[2] | ((unsigned)l[3] << 16);
        lv.z = (unsigned)l[4] | ((unsigned)l[5] << 16);
        lv.w = (unsigned)l[6] | ((unsigned)l[7] << 16);
        size_t ro = (size_t)(rb + tr * 4 + i) * 64 + tc * 8;
        *(uint4*)&zqh[ro] = hv;
        *(uint4*)&zql[ro] = lv;
    }
}

// ---------------- K3: split-bf16 MFMA distance + top-2, P-split x2 ----------------
// block = 256 thr = 4 waves; block covers 64 rows x 4096 pages (half of P)
// grid = 1024 -> 4 blocks/CU, 4 waves/SIMD (was 2: latency exposed)
// per-element top-2 via min/max (6 VALU vs old 10 cndmask ladder); i2 dropped
// (exact ties give d2==d1 -> flagged -> exact recheck keeps first-index rule)
// staging: slot = tid&63 -> linear ds_write_b128, kills the 4-way write conflict
__global__ __launch_bounds__(256) void k3_argmin_mfma(
    const unsigned short* __restrict__ zqh, const unsigned short* __restrict__ zql,
    const unsigned short* __restrict__ cnh, const unsigned short* __restrict__ cnl,
    const float* __restrict__ cc, float4* __restrict__ d12) {
    __shared__ unsigned short lfrag[8 * 4 * 64 * 8];   // [nt][f][slot][8] = 32 KB
    __shared__ float lcc[128];
    int tid = threadIdx.x;
    int w = tid >> 6, lane = tid & 63;
    int col = lane & 15, quad = lane >> 4;
    int rb = (blockIdx.x & 511) * 64;
    int ph = blockIdx.x >> 9;            // which half of P
    int wrow = rb + w * 16;
    int p0 = ph * (P / 2);

    // A-frags (direct from global, once): A[m=lane&15][k=quad*8+j]
    short8 ah[2], al[2];
#pragma unroll
    for (int kf = 0; kf < 2; ++kf) {
        size_t off = (size_t)(wrow + col) * 64 + kf * 32 + quad * 8;
        ah[kf] = *(const short8*)&zqh[off];
        al[kf] = *(const short8*)&zql[off];
    }

    float d1[4], d2[4]; int i1[4];
#pragma unroll
    for (int s = 0; s < 4; ++s) { d1[s] = 3.4e38f; d2[s] = 3.4e38f; i1[s] = 0; }

    // staging role: slot = sq*16+scol = tid&63 (linear LDS write, conflict-free);
    // global reads: per quarter-wave 16 pages x 16B, wave covers full 64B lines
    int sq = (tid >> 4) & 3, scol = tid & 15, sf = tid >> 6;
    const unsigned short* ssrc = (sf & 2) ? cnl : cnh;
    int skf = sf & 1;

    for (int pt = p0; pt < p0 + P / 2; pt += 128) {
        __syncthreads();
#pragma unroll
        for (int nt = 0; nt < 8; ++nt) {
            int p = pt + nt * 16 + scol;
            uint4 dv = *(const uint4*)&ssrc[(size_t)p * 64 + skf * 32 + sq * 8];
            *(uint4*)&lfrag[(((nt * 4 + sf) * 64) + sq * 16 + scol) * 8] = dv;
        }
        if (tid < 128) lcc[tid] = cc[pt + tid];
        __syncthreads();
#pragma unroll 4
        for (int nt = 0; nt < 8; ++nt) {
            short8 bh0 = *(const short8*)&lfrag[((nt * 4 + 0) * 64 + lane) * 8];
            short8 bh1 = *(const short8*)&lfrag[((nt * 4 + 1) * 64 + lane) * 8];
            short8 bl0 = *(const short8*)&lfrag[((nt * 4 + 2) * 64 + lane) * 8];
            short8 bl1 = *(const short8*)&lfrag[((nt * 4 + 3) * 64 + lane) * 8];
            float ccv = lcc[nt * 16 + col];
            int p = pt + nt * 16 + col;
            // two independent 3-deep MFMA chains (k-half 0 -> a0, k-half 1 -> a1)
            f32x4 a0 = {0.f, 0.f, 0.f, 0.f}, a1 = {0.f, 0.f, 0.f, 0.f};
            a0 = __builtin_amdgcn_mfma_f32_16x16x32_bf16(ah[0], bh0, a0, 0, 0, 0);
            a1 = __builtin_amdgcn_mfma_f32_16x16x32_bf16(ah[1], bh1, a1, 0, 0, 0);
            a0 = __builtin_amdgcn_mfma_f32_16x16x32_bf16(ah[0], bl0, a0, 0, 0, 0);
            a1 = __builtin_amdgcn_mfma_f32_16x16x32_bf16(ah[1], bl1, a1, 0, 0, 0);
            a0 = __builtin_amdgcn_mfma_f32_16x16x32_bf16(al[0], bh0, a0, 0, 0, 0);
            a1 = __builtin_amdgcn_mfma_f32_16x16x32_bf16(al[1], bh1, a1, 0, 0, 0);
#pragma unroll
            for (int s = 0; s < 4; ++s) {
                float d = fmaf(a0[s], -2.0f, fmaf(a1[s], -2.0f, ccv));
                bool lt = d < d1[s];                       // strict <: first (lowest p) wins
                i1[s] = lt ? p : i1[s];
                d2[s] = fminf(d2[s], fmaxf(d1[s], d));     // uses OLD d1
                d1[s] = fminf(d1[s], d);
            }
        }
    }
    // merge top-2 across the 16 cols sharing each row (xor 1,2,4,8 stays in-quad)
#pragma unroll
    for (int s = 0; s < 4; ++s) {
        float a1v = d1[s], a2v = d2[s]; int ai = i1[s];
#pragma unroll
        for (int m = 1; m <= 8; m <<= 1) {
            float b1 = __shfl_xor(a1v, m); int bi = __shfl_xor(ai, m);
            float b2 = __shfl_xor(a2v, m);
            float n1 = fminf(a1v, b1);
            a2v = fminf(fmaxf(a1v, b1), fminf(a2v, b2));
            ai = (b1 < a1v) ? bi : ai;   // exact cross-lane tie -> d2==d1 -> flagged anyway
            a1v = n1;
        }
        if (col == 0) {
            int row = wrow + quad * 4 + s;
            d12[ph * N + row] = make_float4(a1v, a2v, __int_as_float(ai), 0.f);
        }
    }
}

// ---------------- K3m: merge the two P-halves, write idx, flag near-ties ----------
__global__ __launch_bounds__(256) void k3m_merge(
    const float4* __restrict__ d12, int* __restrict__ idx_ws, float* __restrict__ idx_out,
    int* __restrict__ qn, int* __restrict__ qlist) {
    int row = blockIdx.x * 256 + threadIdx.x;
    float4 a = d12[row];
    float4 b = d12[N + row];
    bool bw = b.x < a.x;                 // tie -> keep half 0 (lower pages); flagged anyway
    float m1 = bw ? b.x : a.x;
    int i1 = bw ? __float_as_int(b.z) : __float_as_int(a.z);
    float m2 = fminf(fmaxf(a.x, b.x), fminf(a.y, b.y));
    idx_ws[row] = i1;
    idx_out[row] = (float)i1;
    if (m2 - m1 < TAU) {                 // near-tie: exact fp32 recheck
        int qi = atomicAdd(qn, 1);
        qlist[qi] = row;
    }
}

// ---------------- K3r: exact fp32 full-row argmin for flagged rows ----------------
// One queue entry per block; row cached in LDS (broadcast reads, no VGPR array,
// no spill — R2's zr[64]-in-registers spilled at VGPR=48 and ran 1888 us).
__global__ __launch_bounds__(256) void k3_recheck(
    const float* __restrict__ zqT, const float* __restrict__ cnT,
    const float* __restrict__ cc, const int* __restrict__ qn,
    const int* __restrict__ qlist, int* __restrict__ idx_ws, float* __restrict__ idx_out) {
    __shared__ float zrow[64];
    __shared__ float bv[4];
    __shared__ int   bi4[4];
    int tid = threadIdx.x, w = tid >> 6, lane = tid & 63;
    int nq = qn[0];
    for (int e = blockIdx.x; e < nq; e += gridDim.x) {
        int row = qlist[e];
        __syncthreads();    // protect zrow/bv from previous iteration readers
        if (tid < 64) zrow[tid] = zqT[(size_t)tid * N + row];
        __syncthreads();
        float best = 3.4e38f; int bp = 0;
        for (int pb = w * 2048; pb < (w + 1) * 2048; pb += 64) {
            int p = pb + lane;
            float a0 = 0.f, a1 = 0.f, a2 = 0.f, a3 = 0.f;
#pragma unroll
            for (int k = 0; k < 64; k += 4) {
                a0 = fmaf(zrow[k + 0], cnT[(size_t)(k + 0) * P + p], a0);
                a1 = fmaf(zrow[k + 1], cnT[(size_t)(k + 1) * P + p], a1);
                a2 = fmaf(zrow[k + 2], cnT[(size_t)(k + 2) * P + p], a2);
                a3 = fmaf(zrow[k + 3], cnT[(size_t)(k + 3) * P + p], a3);
            }
            float d = fmaf((a0 + a1) + (a2 + a3), -2.0f, cc[p]);
            if (d < best) { best = d; bp = p; }   // per-lane p ascending: strict < keeps first
        }
#pragma unroll
        for (int m = 1; m < 64; m <<= 1) {
            float ob = __shfl_xor(best, m); int op = __shfl_xor(bp, m);
            if (ob < best || (ob == best && op < bp)) { best = ob; bp = op; }
        }
        if (lane == 0) { bv[w] = best; bi4[w] = bp; }
        __syncthreads();
        if (tid == 0) {
            float b = bv[0]; int pi = bi4[0];
#pragma unroll
            for (int ww = 1; ww < 4; ++ww)
                if (bv[ww] < b || (bv[ww] == b && bi4[ww] < pi)) { b = bv[ww]; pi = bi4[ww]; }
            idx_ws[row] = pi; idx_out[row] = (float)pi;
        }
    }
}

// ---------------- K3b: gather codesT[k][r] = cnT[k][idx[r]] ----------------
__global__ __launch_bounds__(256) void k3b_gather(
    const float* __restrict__ cnT, const int* __restrict__ idx, float* __restrict__ codesT) {
    for (size_t i = (size_t)blockIdx.x * 256 + threadIdx.x; i < (size_t)C * N;
         i += (size_t)gridDim.x * 256) {
        int k = (int)(i >> 15);          // N = 2^15
        int r = (int)(i & (N - 1));
        codesT[i] = cnT[(size_t)k * P + idx[r]];
    }
}

// ---------------- K4: out = codes @ w_out^T + b_out ----------------
__global__ __launch_bounds__(256) void k4_out(
    const float* __restrict__ codesT, const float* __restrict__ w_out,
    const float* __restrict__ b_out, float* __restrict__ out) {
    __shared__ float cds[64 * 64];
    __shared__ float wo[64 * 65];
    int tid = threadIdx.x;
    int tx = tid & 15;
    int ty = tid >> 4;
    int rb = blockIdx.x * 64;

    for (int i = tid; i < 64 * 64; i += 256) {
        int k = i >> 6, r = i & 63;
        cds[k * 64 + r] = codesT[(size_t)k * N + rb + r];
    }
    for (int ft = 0; ft < F; ft += 64) {
        __syncthreads();
        for (int i = tid; i < 64 * 64; i += 256) {
            int k = i & 63, f = i >> 6;
            wo[k * 65 + f] = w_out[(size_t)(ft + f) * C + k];
        }
        __syncthreads();
        float acc[4][4];
#pragma unroll
        for (int i = 0; i < 4; ++i)
#pragma unroll
            for (int j = 0; j < 4; ++j) acc[i][j] = 0.f;
#pragma unroll 8
        for (int k = 0; k < 64; ++k) {
            float4 cf = *(const float4*)&cds[k * 64 + ty * 4];
            float cr[4] = {cf.x, cf.y, cf.z, cf.w};
            float wv[4];
#pragma unroll
            for (int j = 0; j < 4; ++j) wv[j] = wo[k * 65 + tx * 4 + j];
#pragma unroll
            for (int i = 0; i < 4; ++i)
#pragma unroll
                for (int j = 0; j < 4; ++j)
                    acc[i][j] = fmaf(cr[i], wv[j], acc[i][j]);
        }
#pragma unroll
        for (int i = 0; i < 4; ++i) {
            int r = rb + ty * 4 + i;
            float4 o;
            o.x = acc[i][0] + b_out[ft + tx * 4 + 0];
            o.y = acc[i][1] + b_out[ft + tx * 4 + 1];
            o.z = acc[i][2] + b_out[ft + tx * 4 + 2];
            o.w = acc[i][3] + b_out[ft + tx * 4 + 3];
            *(float4*)&out[(size_t)r * F + ft + tx * 4] = o;
        }
    }
}

// ---------------- K5: loss partial sums ----------------
__global__ __launch_bounds__(256) void k5_loss(
    const float* __restrict__ zqT, const float* __restrict__ codesT, float* __restrict__ acc) {
    float s = 0.f;
    for (size_t i = (size_t)blockIdx.x * 256 + threadIdx.x; i < (size_t)C * N;
         i += (size_t)gridDim.x * 256) {
        float d = zqT[i] - codesT[i];
        s = fmaf(d, d, s);
    }
#pragma unroll
    for (int off = 32; off > 0; off >>= 1) s += __shfl_xor(s, off);
    __shared__ float wsum[4];
    int lane = threadIdx.x & 63, wv = threadIdx.x >> 6;
    if (lane == 0) wsum[wv] = s;
    __syncthreads();
    if (threadIdx.x == 0) atomicAdd(acc, wsum[0] + wsum[1] + wsum[2] + wsum[3]);
}

// ---------------- K6: finalize loss ----------------
__global__ void k6_finalize(const float* __restrict__ acc, float* __restrict__ loss_out) {
    float m = acc[0] / (float)(C * N);
    loss_out[0] = 0.25f * m + m;   // BETA*mean + mean
}

extern "C" void kernel_launch(void* const* d_in, const int* in_sizes, int n_in,
                              void* d_out, int out_size, void* d_ws, size_t ws_size,
                              hipStream_t stream) {
    const float* z      = (const float*)d_in[0];
    const float* w_in   = (const float*)d_in[1];
    const float* b_in   = (const float*)d_in[2];
    const float* w_out  = (const float*)d_in[3];
    const float* b_out  = (const float*)d_in[4];
    const float* cb     = (const float*)d_in[5];
    float* out = (float*)d_out;
    float* ws  = (float*)d_ws;

    unsigned short* cnh = (unsigned short*)(ws + WS_CNH);
    unsigned short* cnl = (unsigned short*)(ws + WS_CNL);
    unsigned short* zqh = (unsigned short*)(ws + WS_ZQH);
    unsigned short* zql = (unsigned short*)(ws + WS_ZQL);

    hipMemsetAsync(ws + WS_QN, 0, 2 * sizeof(float), stream);   // qn + loss acc
    k1_norm_codebook<<<P / 256, 256, 0, stream>>>(cb, ws + WS_CNT, ws + WS_CC, cnh, cnl);
    k2_project<<<N / 128, 256, 0, stream>>>(z, w_in, b_in, ws + WS_ZQT, zqh, zql);
    k3_argmin_mfma<<<1024, 256, 0, stream>>>(zqh, zql, cnh, cnl, ws + WS_CC,
                                             (float4*)(ws + WS_D12));
    k3m_merge<<<N / 256, 256, 0, stream>>>((const float4*)(ws + WS_D12),
                                           (int*)(ws + WS_IDX), out + OUT_IDX_OFF,
                                           (int*)(ws + WS_QN), (int*)(ws + WS_QLIST));
    k3_recheck<<<512, 256, 0, stream>>>(ws + WS_ZQT, ws + WS_CNT, ws + WS_CC,
                                        (const int*)(ws + WS_QN), (const int*)(ws + WS_QLIST),
                                        (int*)(ws + WS_IDX), out + OUT_IDX_OFF);
    k3b_gather<<<2048, 256, 0, stream>>>(ws + WS_CNT, (const int*)(ws + WS_IDX), ws + WS_CODEST);
    k4_out<<<N / 64, 256, 0, stream>>>(ws + WS_CODEST, w_out, b_out, out);
    k5_loss<<<2048, 256, 0, stream>>>(ws + WS_ZQT, ws + WS_CODEST, ws + WS_ACC);
    k6_finalize<<<1, 1, 0, stream>>>(ws + WS_ACC, out + OUT_LOSS_OFF);
}

// Round 3
// 621.734 us; speedup vs baseline: 1.1499x; 1.0730x over previous
//
#include <hip/hip_runtime.h>

#define N 32768
#define F 768
#define C 64
#define P 8192
#define TAU 1e-3f

typedef __attribute__((ext_vector_type(8))) short short8;
typedef __attribute__((ext_vector_type(4))) float f32x4;

// ---------------- workspace layout (float offsets) ----------------
#define WS_CNT    0                        // cnT   fp32 [C][P] k-major (gather+recheck)
#define WS_CC     (WS_CNT + C*P)           // cc    [P]
#define WS_ZQT    (WS_CC + P)              // zqT   fp32 [C][N] k-major (loss+recheck)
#define WS_CODEST (WS_ZQT + C*N)           // codesT[C][N]
#define WS_IDX    (WS_CODEST + C*N)        // idx   [N] int
#define WS_QN     (WS_IDX + N)             // queue count (int)
#define WS_ACC    (WS_QN + 1)              // loss accumulator
#define WS_QLIST  (WS_ACC + 1)             // queue [N] int
#define WS_CNH    ((WS_QLIST + N + 3) & ~3)  // cn_hi bf16 [P][C] row-major
#define WS_CNL    (WS_CNH + (C*P)/2)       // cn_lo bf16 [P][C]
#define WS_ZQH    (WS_CNL + (C*P)/2)       // zq_hi bf16 [N][C] row-major
#define WS_ZQL    (WS_ZQH + (C*N)/2)       // zq_lo bf16 [N][C]
#define WS_D12    (WS_ZQL + (C*N)/2)       // float4 [4][N]: (s1, s2, i1_bits, pad), s = zq.cn
// end = WS_D12 + 4*N*4 ≈ 7.94M floats ≈ 31.8 MB

#define OUT_LOSS_OFF (N*F)
#define OUT_IDX_OFF  (N*F + 1)

__device__ inline unsigned short f2bf(float x) {   // fp32 -> bf16 RNE
    union { float f; unsigned u; } v; v.f = x;
    unsigned r = v.u + 0x7fffu + ((v.u >> 16) & 1u);
    return (unsigned short)(r >> 16);
}
__device__ inline float bf2f(unsigned short b) {
    union { unsigned u; float f; } v; v.u = ((unsigned)b) << 16;
    return v.f;
}

// ---------------- K1: normalize codebook -> cnT [C][P], cc, cn_hi/lo [P][C] ----
__global__ __launch_bounds__(256) void k1_norm_codebook(
    const float* __restrict__ cb, float* __restrict__ cnT, float* __restrict__ cc,
    unsigned short* __restrict__ cnh, unsigned short* __restrict__ cnl) {
    int p = blockIdx.x * 256 + threadIdx.x;   // one thread per page
    const float4* cb4 = (const float4*)(cb + (size_t)p * C);
    float4 v[16];
    float ss = 0.f;
#pragma unroll
    for (int i = 0; i < 16; ++i) {
        v[i] = cb4[i];
        ss += v[i].x * v[i].x + v[i].y * v[i].y + v[i].z * v[i].z + v[i].w * v[i].w;
    }
    float nrm = sqrtf(ss);
    float s2 = 0.f;
    unsigned short hb[64], lb[64];
#pragma unroll
    for (int i = 0; i < 16; ++i) {
        float c4[4] = {v[i].x / nrm, v[i].y / nrm, v[i].z / nrm, v[i].w / nrm};
#pragma unroll
        for (int j = 0; j < 4; ++j) {
            cnT[(size_t)(i * 4 + j) * P + p] = c4[j];
            s2 += c4[j] * c4[j];
            unsigned short h = f2bf(c4[j]);
            hb[i * 4 + j] = h;
            lb[i * 4 + j] = f2bf(c4[j] - bf2f(h));
        }
    }
    cc[p] = s2;
#pragma unroll
    for (int i = 0; i < 8; ++i) {
        uint4 hv, lv;
        hv.x = (unsigned)hb[i*8+0] | ((unsigned)hb[i*8+1] << 16);
        hv.y = (unsigned)hb[i*8+2] | ((unsigned)hb[i*8+3] << 16);
        hv.z = (unsigned)hb[i*8+4] | ((unsigned)hb[i*8+5] << 16);
        hv.w = (unsigned)hb[i*8+6] | ((unsigned)hb[i*8+7] << 16);
        lv.x = (unsigned)lb[i*8+0] | ((unsigned)lb[i*8+1] << 16);
        lv.y = (unsigned)lb[i*8+2] | ((unsigned)lb[i*8+3] << 16);
        lv.z = (unsigned)lb[i*8+4] | ((unsigned)lb[i*8+5] << 16);
        lv.w = (unsigned)lb[i*8+6] | ((unsigned)lb[i*8+7] << 16);
        *(uint4*)&cnh[(size_t)p * 64 + i * 8] = hv;
        *(uint4*)&cnl[(size_t)p * 64 + i * 8] = lv;
    }
}

// ---------------- K2: zq = normalize(z @ w_in^T + b_in) -> zqT, zq_hi/lo ----
__global__ __launch_bounds__(256) void k2_project(
    const float* __restrict__ z, const float* __restrict__ w_in, const float* __restrict__ b_in,
    float* __restrict__ zqT, unsigned short* __restrict__ zqh, unsigned short* __restrict__ zql) {
    __shared__ float zrow[128 * 33];
    __shared__ float wrow[64 * 32];
    __shared__ float red[128 * 9];
    int tid = threadIdx.x;
    int tr = tid & 31;        // row group: 4 rows each -> 128 rows
    int tc = tid >> 5;        // code group: 8 codes each -> 64 codes
    int rb = blockIdx.x * 128;

    float y[4][8];
#pragma unroll
    for (int i = 0; i < 4; ++i)
#pragma unroll
        for (int j = 0; j < 8; ++j) y[i][j] = 0.f;

    for (int kt = 0; kt < F; kt += 32) {
        __syncthreads();
        for (int i = tid; i < 128 * 32; i += 256) {
            int r = i >> 5, k = i & 31;
            zrow[r * 33 + k] = z[(size_t)(rb + r) * F + kt + k];
        }
        for (int i = tid; i < 64 * 32; i += 256) {
            int c = i >> 5, k = i & 31;
            wrow[c * 32 + k] = w_in[(size_t)c * F + kt + k];
        }
        __syncthreads();
#pragma unroll
        for (int k4 = 0; k4 < 8; ++k4) {
            float zs[4][4];
#pragma unroll
            for (int i = 0; i < 4; ++i)
#pragma unroll
                for (int kk = 0; kk < 4; ++kk)
                    zs[i][kk] = zrow[(tr * 4 + i) * 33 + k4 * 4 + kk];
#pragma unroll
            for (int j = 0; j < 8; ++j) {
                float4 wv = *(const float4*)&wrow[(tc * 8 + j) * 32 + k4 * 4];
#pragma unroll
                for (int i = 0; i < 4; ++i)
                    y[i][j] = fmaf(zs[i][3], wv.w,
                              fmaf(zs[i][2], wv.z,
                              fmaf(zs[i][1], wv.y,
                              fmaf(zs[i][0], wv.x, y[i][j]))));
            }
        }
    }
#pragma unroll
    for (int j = 0; j < 8; ++j) {
        float b = b_in[tc * 8 + j];
#pragma unroll
        for (int i = 0; i < 4; ++i) y[i][j] += b;
    }
    __syncthreads();
#pragma unroll
    for (int i = 0; i < 4; ++i) {
        float s = 0.f;
#pragma unroll
        for (int j = 0; j < 8; ++j) s += y[i][j] * y[i][j];
        red[(tr * 4 + i) * 9 + tc] = s;
    }
    __syncthreads();
    float nrm[4];
#pragma unroll
    for (int i = 0; i < 4; ++i) {
        float t = 0.f;
#pragma unroll
        for (int t8 = 0; t8 < 8; ++t8) t += red[(tr * 4 + i) * 9 + t8];
        nrm[i] = sqrtf(t);
    }
    float q[4][8];
#pragma unroll
    for (int i = 0; i < 4; ++i)
#pragma unroll
        for (int j = 0; j < 8; ++j) q[i][j] = y[i][j] / nrm[i];
    // store transposed fp32: zqT[c][rb + tr*4 .. +3]
#pragma unroll
    for (int j = 0; j < 8; ++j) {
        int c = tc * 8 + j;
        float4 o = make_float4(q[0][j], q[1][j], q[2][j], q[3][j]);
        *(float4*)&zqT[(size_t)c * N + rb + tr * 4] = o;
    }
    // store row-major bf16 hi/lo: zqh/zql[row][64]
#pragma unroll
    for (int i = 0; i < 4; ++i) {
        unsigned short h[8], l[8];
#pragma unroll
        for (int j = 0; j < 8; ++j) {
            h[j] = f2bf(q[i][j]);
            l[j] = f2bf(q[i][j] - bf2f(h[j]));
        }
        uint4 hv, lv;
        hv.x = (unsigned)h[0] | ((unsigned)h[1] << 16);
        hv.y = (unsigned)h[2] | ((unsigned)h[3] << 16);
        hv.z = (unsigned)h[4] | ((unsigned)h[5] << 16);
        hv.w = (unsigned)h[6] | ((unsigned)h[7] << 16);
        lv.x = (unsigned)l[0] | ((unsigned)l[1] << 16);
        lv.y = (unsigned)l[2] | ((unsigned)l[3] << 16);
        lv.z = (unsigned)l[4] | ((unsigned)l[5] << 16);
        lv.w = (unsigned)l[6] | ((unsigned)l[7] << 16);
        size_t ro = (size_t)(rb + tr * 4 + i) * 64 + tc * 8;
        *(uint4*)&zqh[ro] = hv;
        *(uint4*)&zql[ro] = lv;
    }
}

// ---------------- K3: split-bf16 MFMA similarity + top-2, 32 rows/wave ----------------
// block = 256 thr = 4 waves; block covers 128 rows x 2048 pages (P/4)
// grid = 256 row-blocks x 4 P-parts = 1024 -> 4 blocks/CU, 16 waves/CU
// each wave owns 2 m-tiles (32 rows): every B ds_read feeds 12 MFMAs (was 6)
// scan maximizes s = zq.cn (cc==1 +-4e-6 for normalized codes; absorbed in flag
// threshold, recheck uses exact fp32 d with cc). update = 5 VALU/element.
// staging: slot = tid&63 -> linear ds_write_b128, conflict-free (R1-proven)
__global__ __launch_bounds__(256, 4) void k3_argmin_mfma(
    const unsigned short* __restrict__ zqh, const unsigned short* __restrict__ zql,
    const unsigned short* __restrict__ cnh, const unsigned short* __restrict__ cnl,
    float4* __restrict__ d12) {
    __shared__ unsigned short lfrag[8 * 4 * 64 * 8];   // [nt][f][slot][8] = 32 KB
    int tid = threadIdx.x;
    int w = tid >> 6, lane = tid & 63;
    int col = lane & 15, quad = lane >> 4;
    int rb = (blockIdx.x & 255) * 128;
    int ph = blockIdx.x >> 8;            // which quarter of P
    int wrow = rb + w * 32;              // wave: rows [wrow, wrow+32)
    int p0 = ph * (P / 4);

    // A-frags (direct from global, once): A[m=lane&15][k=quad*8+j], 2 m-tiles
    short8 ah[2][2], al[2][2];
#pragma unroll
    for (int mm = 0; mm < 2; ++mm)
#pragma unroll
        for (int kf = 0; kf < 2; ++kf) {
            size_t off = (size_t)(wrow + mm * 16 + col) * 64 + kf * 32 + quad * 8;
            ah[mm][kf] = *(const short8*)&zqh[off];
            al[mm][kf] = *(const short8*)&zql[off];
        }

    float s1[8], s2[8]; int i1[8];       // r = mm*4+s, row = wrow + mm*16 + quad*4 + s
#pragma unroll
    for (int r = 0; r < 8; ++r) { s1[r] = -3.4e38f; s2[r] = -3.4e38f; i1[r] = 0; }

    // staging role: slot = tid&63 (linear LDS write, conflict-free);
    // wave sf stages quadrant sf; global: 16B/lane, wave covers 16 pages x 64B
    int sq = (tid >> 4) & 3, scol = tid & 15, sf = w;  // sf: 0=hi k0,1=hi k1,2=lo k0,3=lo k1
    const unsigned short* ssrc = (sf & 2) ? cnl : cnh;
    int skf = sf & 1;

    for (int pt = p0; pt < p0 + P / 4; pt += 128) {
        __syncthreads();
#pragma unroll
        for (int nt = 0; nt < 8; ++nt) {
            int p = pt + nt * 16 + scol;
            uint4 dv = *(const uint4*)&ssrc[(size_t)p * 64 + skf * 32 + sq * 8];
            *(uint4*)&lfrag[((nt * 4 + sf) * 64 + (tid & 63)) * 8] = dv;
        }
        __syncthreads();
#pragma unroll 2
        for (int nt = 0; nt < 8; ++nt) {
            short8 bh0 = *(const short8*)&lfrag[((nt * 4 + 0) * 64 + lane) * 8];
            short8 bh1 = *(const short8*)&lfrag[((nt * 4 + 1) * 64 + lane) * 8];
            short8 bl0 = *(const short8*)&lfrag[((nt * 4 + 2) * 64 + lane) * 8];
            short8 bl1 = *(const short8*)&lfrag[((nt * 4 + 3) * 64 + lane) * 8];
            int p = pt + nt * 16 + col;
#pragma unroll
            for (int mm = 0; mm < 2; ++mm) {
                // single 6-deep chain per m-tile (2 independent chains per nt)
                f32x4 acc = {0.f, 0.f, 0.f, 0.f};
                acc = __builtin_amdgcn_mfma_f32_16x16x32_bf16(ah[mm][0], bh0, acc, 0, 0, 0);
                acc = __builtin_amdgcn_mfma_f32_16x16x32_bf16(ah[mm][1], bh1, acc, 0, 0, 0);
                acc = __builtin_amdgcn_mfma_f32_16x16x32_bf16(ah[mm][0], bl0, acc, 0, 0, 0);
                acc = __builtin_amdgcn_mfma_f32_16x16x32_bf16(ah[mm][1], bl1, acc, 0, 0, 0);
                acc = __builtin_amdgcn_mfma_f32_16x16x32_bf16(al[mm][0], bh0, acc, 0, 0, 0);
                acc = __builtin_amdgcn_mfma_f32_16x16x32_bf16(al[mm][1], bh1, acc, 0, 0, 0);
#pragma unroll
                for (int s = 0; s < 4; ++s) {
                    float sv = acc[s];
                    int r = mm * 4 + s;
                    bool gt = sv > s1[r];                    // strict >: first page wins
                    i1[r] = gt ? p : i1[r];
                    s2[r] = fmaxf(s2[r], fminf(s1[r], sv));  // uses OLD s1
                    s1[r] = fmaxf(s1[r], sv);
                }
            }
        }
    }
    // merge top-2 across the 16 cols sharing each row (xor 1,2,4,8 stays in-quad)
#pragma unroll
    for (int r = 0; r < 8; ++r) {
        float a1v = s1[r], a2v = s2[r]; int ai = i1[r];
#pragma unroll
        for (int m = 1; m <= 8; m <<= 1) {
            float b1 = __shfl_xor(a1v, m); int bi = __shfl_xor(ai, m);
            float b2 = __shfl_xor(a2v, m);
            float n1 = fmaxf(a1v, b1);
            a2v = fmaxf(fminf(a1v, b1), fmaxf(a2v, b2));
            ai = (b1 > a1v) ? bi : ai;   // exact cross-lane tie -> s2==s1 -> flagged anyway
            a1v = n1;
        }
        if (col == 0) {
            int row = wrow + (r >> 2) * 16 + quad * 4 + (r & 3);
            d12[ph * N + row] = make_float4(a1v, a2v, __int_as_float(ai), 0.f);
        }
    }
}

// ---------------- K3m: merge the four P-parts, write idx, flag near-ties ----------
__global__ __launch_bounds__(256) void k3m_merge(
    const float4* __restrict__ d12, int* __restrict__ idx_ws, float* __restrict__ idx_out,
    int* __restrict__ qn, int* __restrict__ qlist) {
    int row = blockIdx.x * 256 + threadIdx.x;
    float4 a = d12[row];
    float m1 = a.x, m2 = a.y; int i1 = __float_as_int(a.z);
#pragma unroll
    for (int ph = 1; ph < 4; ++ph) {
        float4 b = d12[ph * N + row];
        m2 = fmaxf(fminf(m1, b.x), fmaxf(m2, b.y));
        if (b.x > m1) { i1 = __float_as_int(b.z); m1 = b.x; }  // tie keeps lower part; flagged anyway
    }
    idx_ws[row] = i1;
    idx_out[row] = (float)i1;
    // d-gap = 2*(m1-m2) +- 4e-6 (cc variation); flag if could be < TAU
    if (m1 - m2 < 0.5f * TAU + 2e-6f) {
        int qi = atomicAdd(qn, 1);
        qlist[qi] = row;
    }
}

// ---------------- K3r: exact fp32 full-row argmin for flagged rows ----------------
// One queue entry per block; row cached in LDS (broadcast reads, no VGPR array,
// no spill — R2's zr[64]-in-registers spilled at VGPR=48 and ran 1888 us).
__global__ __launch_bounds__(256) void k3_recheck(
    const float* __restrict__ zqT, const float* __restrict__ cnT,
    const float* __restrict__ cc, const int* __restrict__ qn,
    const int* __restrict__ qlist, int* __restrict__ idx_ws, float* __restrict__ idx_out) {
    __shared__ float zrow[64];
    __shared__ float bv[4];
    __shared__ int   bi4[4];
    int tid = threadIdx.x, w = tid >> 6, lane = tid & 63;
    int nq = qn[0];
    for (int e = blockIdx.x; e < nq; e += gridDim.x) {
        int row = qlist[e];
        __syncthreads();    // protect zrow/bv from previous iteration readers
        if (tid < 64) zrow[tid] = zqT[(size_t)tid * N + row];
        __syncthreads();
        float best = 3.4e38f; int bp = 0;
        for (int pb = w * 2048; pb < (w + 1) * 2048; pb += 64) {
            int p = pb + lane;
            float a0 = 0.f, a1 = 0.f, a2 = 0.f, a3 = 0.f;
#pragma unroll
            for (int k = 0; k < 64; k += 4) {
                a0 = fmaf(zrow[k + 0], cnT[(size_t)(k + 0) * P + p], a0);
                a1 = fmaf(zrow[k + 1], cnT[(size_t)(k + 1) * P + p], a1);
                a2 = fmaf(zrow[k + 2], cnT[(size_t)(k + 2) * P + p], a2);
                a3 = fmaf(zrow[k + 3], cnT[(size_t)(k + 3) * P + p], a3);
            }
            float d = fmaf((a0 + a1) + (a2 + a3), -2.0f, cc[p]);
            if (d < best) { best = d; bp = p; }   // per-lane p ascending: strict < keeps first
        }
#pragma unroll
        for (int m = 1; m < 64; m <<= 1) {
            float ob = __shfl_xor(best, m); int op = __shfl_xor(bp, m);
            if (ob < best || (ob == best && op < bp)) { best = ob; bp = op; }
        }
        if (lane == 0) { bv[w] = best; bi4[w] = bp; }
        __syncthreads();
        if (tid == 0) {
            float b = bv[0]; int pi = bi4[0];
#pragma unroll
            for (int ww = 1; ww < 4; ++ww)
                if (bv[ww] < b || (bv[ww] == b && bi4[ww] < pi)) { b = bv[ww]; pi = bi4[ww]; }
            idx_ws[row] = pi; idx_out[row] = (float)pi;
        }
    }
}

// ---------------- K3b: gather codesT[k][r] = cnT[k][idx[r]] ----------------
__global__ __launch_bounds__(256) void k3b_gather(
    const float* __restrict__ cnT, const int* __restrict__ idx, float* __restrict__ codesT) {
    for (size_t i = (size_t)blockIdx.x * 256 + threadIdx.x; i < (size_t)C * N;
         i += (size_t)gridDim.x * 256) {
        int k = (int)(i >> 15);          // N = 2^15
        int r = (int)(i & (N - 1));
        codesT[i] = cnT[(size_t)k * P + idx[r]];
    }
}

// ---------------- K4: out = codes @ w_out^T + b_out ----------------
__global__ __launch_bounds__(256) void k4_out(
    const float* __restrict__ codesT, const float* __restrict__ w_out,
    const float* __restrict__ b_out, float* __restrict__ out) {
    __shared__ float cds[64 * 64];
    __shared__ float wo[64 * 65];
    int tid = threadIdx.x;
    int tx = tid & 15;
    int ty = tid >> 4;
    int rb = blockIdx.x * 64;

    for (int i = tid; i < 64 * 64; i += 256) {
        int k = i >> 6, r = i & 63;
        cds[k * 64 + r] = codesT[(size_t)k * N + rb + r];
    }
    for (int ft = 0; ft < F; ft += 64) {
        __syncthreads();
        for (int i = tid; i < 64 * 64; i += 256) {
            int k = i & 63, f = i >> 6;
            wo[k * 65 + f] = w_out[(size_t)(ft + f) * C + k];
        }
        __syncthreads();
        float acc[4][4];
#pragma unroll
        for (int i = 0; i < 4; ++i)
#pragma unroll
            for (int j = 0; j < 4; ++j) acc[i][j] = 0.f;
#pragma unroll 8
        for (int k = 0; k < 64; ++k) {
            float4 cf = *(const float4*)&cds[k * 64 + ty * 4];
            float cr[4] = {cf.x, cf.y, cf.z, cf.w};
            float wv[4];
#pragma unroll
            for (int j = 0; j < 4; ++j) wv[j] = wo[k * 65 + tx * 4 + j];
#pragma unroll
            for (int i = 0; i < 4; ++i)
#pragma unroll
                for (int j = 0; j < 4; ++j)
                    acc[i][j] = fmaf(cr[i], wv[j], acc[i][j]);
        }
#pragma unroll
        for (int i = 0; i < 4; ++i) {
            int r = rb + ty * 4 + i;
            float4 o;
            o.x = acc[i][0] + b_out[ft + tx * 4 + 0];
            o.y = acc[i][1] + b_out[ft + tx * 4 + 1];
            o.z = acc[i][2] + b_out[ft + tx * 4 + 2];
            o.w = acc[i][3] + b_out[ft + tx * 4 + 3];
            *(float4*)&out[(size_t)r * F + ft + tx * 4] = o;
        }
    }
}

// ---------------- K5: loss partial sums ----------------
__global__ __launch_bounds__(256) void k5_loss(
    const float* __restrict__ zqT, const float* __restrict__ codesT, float* __restrict__ acc) {
    float s = 0.f;
    for (size_t i = (size_t)blockIdx.x * 256 + threadIdx.x; i < (size_t)C * N;
         i += (size_t)gridDim.x * 256) {
        float d = zqT[i] - codesT[i];
        s = fmaf(d, d, s);
    }
#pragma unroll
    for (int off = 32; off > 0; off >>= 1) s += __shfl_xor(s, off);
    __shared__ float wsum[4];
    int lane = threadIdx.x & 63, wv = threadIdx.x >> 6;
    if (lane == 0) wsum[wv] = s;
    __syncthreads();
    if (threadIdx.x == 0) atomicAdd(acc, wsum[0] + wsum[1] + wsum[2] + wsum[3]);
}

// ---------------- K6: finalize loss ----------------
__global__ void k6_finalize(const float* __restrict__ acc, float* __restrict__ loss_out) {
    float m = acc[0] / (float)(C * N);
    loss_out[0] = 0.25f * m + m;   // BETA*mean + mean
}

extern "C" void kernel_launch(void* const* d_in, const int* in_sizes, int n_in,
                              void* d_out, int out_size, void* d_ws, size_t ws_size,
                              hipStream_t stream) {
    const float* z      = (const float*)d_in[0];
    const float* w_in   = (const float*)d_in[1];
    const float* b_in   = (const float*)d_in[2];
    const float* w_out  = (const float*)d_in[3];
    const float* b_out  = (const float*)d_in[4];
    const float* cb     = (const float*)d_in[5];
    float* out = (float*)d_out;
    float* ws  = (float*)d_ws;

    unsigned short* cnh = (unsigned short*)(ws + WS_CNH);
    unsigned short* cnl = (unsigned short*)(ws + WS_CNL);
    unsigned short* zqh = (unsigned short*)(ws + WS_ZQH);
    unsigned short* zql = (unsigned short*)(ws + WS_ZQL);

    hipMemsetAsync(ws + WS_QN, 0, 2 * sizeof(float), stream);   // qn + loss acc
    k1_norm_codebook<<<P / 256, 256, 0, stream>>>(cb, ws + WS_CNT, ws + WS_CC, cnh, cnl);
    k2_project<<<N / 128, 256, 0, stream>>>(z, w_in, b_in, ws + WS_ZQT, zqh, zql);
    k3_argmin_mfma<<<1024, 256, 0, stream>>>(zqh, zql, cnh, cnl, (float4*)(ws + WS_D12));
    k3m_merge<<<N / 256, 256, 0, stream>>>((const float4*)(ws + WS_D12),
                                           (int*)(ws + WS_IDX), out + OUT_IDX_OFF,
                                           (int*)(ws + WS_QN), (int*)(ws + WS_QLIST));
    k3_recheck<<<512, 256, 0, stream>>>(ws + WS_ZQT, ws + WS_CNT, ws + WS_CC,
                                        (const int*)(ws + WS_QN), (const int*)(ws + WS_QLIST),
                                        (int*)(ws + WS_IDX), out + OUT_IDX_OFF);
    k3b_gather<<<2048, 256, 0, stream>>>(ws + WS_CNT, (const int*)(ws + WS_IDX), ws + WS_CODEST);
    k4_out<<<N / 64, 256, 0, stream>>>(ws + WS_CODEST, w_out, b_out, out);
    k5_loss<<<2048, 256, 0, stream>>>(ws + WS_ZQT, ws + WS_CODEST, ws + WS_ACC);
    k6_finalize<<<1, 1, 0, stream>>>(ws + WS_ACC, out + OUT_LOSS_OFF);
}

// Round 4
// 614.052 us; speedup vs baseline: 1.1643x; 1.0125x over previous
//
#include <hip/hip_runtime.h>

#define N 32768
#define F 768
#define C 64
#define P 8192
#define TAU 1e-3f

typedef __attribute__((ext_vector_type(8))) short short8;
typedef __attribute__((ext_vector_type(4))) float f32x4;

// ---------------- workspace layout (float offsets) ----------------
#define WS_CNT    0                        // cnT   fp32 [C][P] k-major (recheck+loss gather)
#define WS_CC     (WS_CNT + C*P)           // cc    [P]
#define WS_ZQT    (WS_CC + P)              // zqT   fp32 [C][N] k-major (loss+recheck)
#define WS_CODEST (WS_ZQT + C*N)           // (unused hole, kept to avoid offset churn)
#define WS_IDX    (WS_CODEST + C*N)        // idx   [N] int
#define WS_QN     (WS_IDX + N)             // queue count (int)
#define WS_ACC    (WS_QN + 1)              // loss accumulator
#define WS_QLIST  (WS_ACC + 1)             // queue [N] int
#define WS_CNH    ((WS_QLIST + N + 3) & ~3)  // cn_hi bf16 [P][C] row-major
#define WS_CNL    (WS_CNH + (C*P)/2)       // cn_lo bf16 [P][C]
#define WS_ZQH    (WS_CNL + (C*P)/2)       // zq_hi bf16 [N][C] row-major
#define WS_ZQL    (WS_ZQH + (C*N)/2)       // zq_lo bf16 [N][C]
#define WS_D12    (WS_ZQL + (C*N)/2)       // float4 [4][N]: (s1, s2, i1_bits, pad), s = zq.cn
#define WS_WOH    (WS_D12 + 16*N)          // w_out hi bf16 [F][C]
#define WS_WOL    (WS_WOH + (F*C)/2)       // w_out lo bf16 [F][C]
// end = WS_WOL + F*C/2 ≈ 7.99M floats ≈ 32.0 MB

#define OUT_LOSS_OFF (N*F)
#define OUT_IDX_OFF  (N*F + 1)

__device__ inline unsigned short f2bf(float x) {   // fp32 -> bf16 RNE
    union { float f; unsigned u; } v; v.f = x;
    unsigned r = v.u + 0x7fffu + ((v.u >> 16) & 1u);
    return (unsigned short)(r >> 16);
}
__device__ inline float bf2f(unsigned short b) {
    union { unsigned u; float f; } v; v.u = ((unsigned)b) << 16;
    return v.f;
}

// ---------------- K1: normalize codebook -> cnT [C][P], cc, cn_hi/lo [P][C] ----
__global__ __launch_bounds__(256) void k1_norm_codebook(
    const float* __restrict__ cb, float* __restrict__ cnT, float* __restrict__ cc,
    unsigned short* __restrict__ cnh, unsigned short* __restrict__ cnl) {
    int p = blockIdx.x * 256 + threadIdx.x;   // one thread per page
    const float4* cb4 = (const float4*)(cb + (size_t)p * C);
    float4 v[16];
    float ss = 0.f;
#pragma unroll
    for (int i = 0; i < 16; ++i) {
        v[i] = cb4[i];
        ss += v[i].x * v[i].x + v[i].y * v[i].y + v[i].z * v[i].z + v[i].w * v[i].w;
    }
    float nrm = sqrtf(ss);
    float s2 = 0.f;
    unsigned short hb[64], lb[64];
#pragma unroll
    for (int i = 0; i < 16; ++i) {
        float c4[4] = {v[i].x / nrm, v[i].y / nrm, v[i].z / nrm, v[i].w / nrm};
#pragma unroll
        for (int j = 0; j < 4; ++j) {
            cnT[(size_t)(i * 4 + j) * P + p] = c4[j];
            s2 += c4[j] * c4[j];
            unsigned short h = f2bf(c4[j]);
            hb[i * 4 + j] = h;
            lb[i * 4 + j] = f2bf(c4[j] - bf2f(h));
        }
    }
    cc[p] = s2;
#pragma unroll
    for (int i = 0; i < 8; ++i) {
        uint4 hv, lv;
        hv.x = (unsigned)hb[i*8+0] | ((unsigned)hb[i*8+1] << 16);
        hv.y = (unsigned)hb[i*8+2] | ((unsigned)hb[i*8+3] << 16);
        hv.z = (unsigned)hb[i*8+4] | ((unsigned)hb[i*8+5] << 16);
        hv.w = (unsigned)hb[i*8+6] | ((unsigned)hb[i*8+7] << 16);
        lv.x = (unsigned)lb[i*8+0] | ((unsigned)lb[i*8+1] << 16);
        lv.y = (unsigned)lb[i*8+2] | ((unsigned)lb[i*8+3] << 16);
        lv.z = (unsigned)lb[i*8+4] | ((unsigned)lb[i*8+5] << 16);
        lv.w = (unsigned)lb[i*8+6] | ((unsigned)lb[i*8+7] << 16);
        *(uint4*)&cnh[(size_t)p * 64 + i * 8] = hv;
        *(uint4*)&cnl[(size_t)p * 64 + i * 8] = lv;
    }
}

// ---------------- K2: zq = normalize(z @ w_in^T + b_in) -> zqT, zq_hi/lo ----
// 64 rows/block -> grid 512 (2 blocks/CU, was 1: latency fully exposed at occ 11.6%)
// rows per thread interleaved {tr, tr+32}: zrow scalar reads have bank stride 1
// (33*4B per row) -> conflict-free; half-waves read same addr -> broadcast.
__global__ __launch_bounds__(256) void k2_project(
    const float* __restrict__ z, const float* __restrict__ w_in, const float* __restrict__ b_in,
    float* __restrict__ zqT, unsigned short* __restrict__ zqh, unsigned short* __restrict__ zql) {
    __shared__ float zrow[64 * 33];
    __shared__ float wrow[64 * 32];
    __shared__ float red[64 * 9];
    int tid = threadIdx.x;
    int tr = tid & 31;        // row lane: rows tr and tr+32
    int tc = tid >> 5;        // code group: 8 codes each -> 64 codes
    int rb = blockIdx.x * 64;

    float y[2][8];
#pragma unroll
    for (int i = 0; i < 2; ++i)
#pragma unroll
        for (int j = 0; j < 8; ++j) y[i][j] = 0.f;

    for (int kt = 0; kt < F; kt += 32) {
        __syncthreads();
        for (int i = tid; i < 64 * 32; i += 256) {
            int r = i >> 5, k = i & 31;
            zrow[r * 33 + k] = z[(size_t)(rb + r) * F + kt + k];
        }
        for (int i = tid; i < 64 * 32; i += 256) {
            int c = i >> 5, k = i & 31;
            wrow[c * 32 + k] = w_in[(size_t)c * F + kt + k];
        }
        __syncthreads();
#pragma unroll
        for (int k4 = 0; k4 < 8; ++k4) {
            float zs[2][4];
#pragma unroll
            for (int i = 0; i < 2; ++i)
#pragma unroll
                for (int kk = 0; kk < 4; ++kk)
                    zs[i][kk] = zrow[(tr + 32 * i) * 33 + k4 * 4 + kk];
#pragma unroll
            for (int j = 0; j < 8; ++j) {
                float4 wv = *(const float4*)&wrow[(tc * 8 + j) * 32 + k4 * 4];
#pragma unroll
                for (int i = 0; i < 2; ++i)
                    y[i][j] = fmaf(zs[i][3], wv.w,
                              fmaf(zs[i][2], wv.z,
                              fmaf(zs[i][1], wv.y,
                              fmaf(zs[i][0], wv.x, y[i][j]))));
            }
        }
    }
#pragma unroll
    for (int j = 0; j < 8; ++j) {
        float b = b_in[tc * 8 + j];
#pragma unroll
        for (int i = 0; i < 2; ++i) y[i][j] += b;
    }
    __syncthreads();
#pragma unroll
    for (int i = 0; i < 2; ++i) {
        float s = 0.f;
#pragma unroll
        for (int j = 0; j < 8; ++j) s += y[i][j] * y[i][j];
        red[(tr + 32 * i) * 9 + tc] = s;
    }
    __syncthreads();
    float nrm[2];
#pragma unroll
    for (int i = 0; i < 2; ++i) {
        float t = 0.f;
#pragma unroll
        for (int t8 = 0; t8 < 8; ++t8) t += red[(tr + 32 * i) * 9 + t8];
        nrm[i] = sqrtf(t);
    }
    float q[2][8];
#pragma unroll
    for (int i = 0; i < 2; ++i)
#pragma unroll
        for (int j = 0; j < 8; ++j) q[i][j] = y[i][j] / nrm[i];
    // store transposed fp32 (scalar; lanes tr consecutive -> 128B segments)
#pragma unroll
    for (int j = 0; j < 8; ++j) {
        int c = tc * 8 + j;
#pragma unroll
        for (int i = 0; i < 2; ++i)
            zqT[(size_t)c * N + rb + tr + 32 * i] = q[i][j];
    }
    // store row-major bf16 hi/lo: zqh/zql[row][64]
#pragma unroll
    for (int i = 0; i < 2; ++i) {
        unsigned short h[8], l[8];
#pragma unroll
        for (int j = 0; j < 8; ++j) {
            h[j] = f2bf(q[i][j]);
            l[j] = f2bf(q[i][j] - bf2f(h[j]));
        }
        uint4 hv, lv;
        hv.x = (unsigned)h[0] | ((unsigned)h[1] << 16);
        hv.y = (unsigned)h[2] | ((unsigned)h[3] << 16);
        hv.z = (unsigned)h[4] | ((unsigned)h[5] << 16);
        hv.w = (unsigned)h[6] | ((unsigned)h[7] << 16);
        lv.x = (unsigned)l[0] | ((unsigned)l[1] << 16);
        lv.y = (unsigned)l[2] | ((unsigned)l[3] << 16);
        lv.z = (unsigned)l[4] | ((unsigned)l[5] << 16);
        lv.w = (unsigned)l[6] | ((unsigned)l[7] << 16);
        size_t ro = (size_t)(rb + tr + 32 * i) * 64 + tc * 8;
        *(uint4*)&zqh[ro] = hv;
        *(uint4*)&zql[ro] = lv;
    }
}

// ---------------- K3: split-bf16 MFMA similarity + top-2, 32 rows/wave ----------------
__global__ __launch_bounds__(256, 4) void k3_argmin_mfma(
    const unsigned short* __restrict__ zqh, const unsigned short* __restrict__ zql,
    const unsigned short* __restrict__ cnh, const unsigned short* __restrict__ cnl,
    float4* __restrict__ d12) {
    __shared__ unsigned short lfrag[8 * 4 * 64 * 8];   // [nt][f][slot][8] = 32 KB
    int tid = threadIdx.x;
    int w = tid >> 6, lane = tid & 63;
    int col = lane & 15, quad = lane >> 4;
    int rb = (blockIdx.x & 255) * 128;
    int ph = blockIdx.x >> 8;            // which quarter of P
    int wrow = rb + w * 32;              // wave: rows [wrow, wrow+32)
    int p0 = ph * (P / 4);

    short8 ah[2][2], al[2][2];
#pragma unroll
    for (int mm = 0; mm < 2; ++mm)
#pragma unroll
        for (int kf = 0; kf < 2; ++kf) {
            size_t off = (size_t)(wrow + mm * 16 + col) * 64 + kf * 32 + quad * 8;
            ah[mm][kf] = *(const short8*)&zqh[off];
            al[mm][kf] = *(const short8*)&zql[off];
        }

    float s1[8], s2[8]; int i1[8];
#pragma unroll
    for (int r = 0; r < 8; ++r) { s1[r] = -3.4e38f; s2[r] = -3.4e38f; i1[r] = 0; }

    int sq = (tid >> 4) & 3, scol = tid & 15, sf = w;
    const unsigned short* ssrc = (sf & 2) ? cnl : cnh;
    int skf = sf & 1;

    for (int pt = p0; pt < p0 + P / 4; pt += 128) {
        __syncthreads();
#pragma unroll
        for (int nt = 0; nt < 8; ++nt) {
            int p = pt + nt * 16 + scol;
            uint4 dv = *(const uint4*)&ssrc[(size_t)p * 64 + skf * 32 + sq * 8];
            *(uint4*)&lfrag[((nt * 4 + sf) * 64 + (tid & 63)) * 8] = dv;
        }
        __syncthreads();
#pragma unroll 2
        for (int nt = 0; nt < 8; ++nt) {
            short8 bh0 = *(const short8*)&lfrag[((nt * 4 + 0) * 64 + lane) * 8];
            short8 bh1 = *(const short8*)&lfrag[((nt * 4 + 1) * 64 + lane) * 8];
            short8 bl0 = *(const short8*)&lfrag[((nt * 4 + 2) * 64 + lane) * 8];
            short8 bl1 = *(const short8*)&lfrag[((nt * 4 + 3) * 64 + lane) * 8];
            int p = pt + nt * 16 + col;
#pragma unroll
            for (int mm = 0; mm < 2; ++mm) {
                f32x4 acc = {0.f, 0.f, 0.f, 0.f};
                acc = __builtin_amdgcn_mfma_f32_16x16x32_bf16(ah[mm][0], bh0, acc, 0, 0, 0);
                acc = __builtin_amdgcn_mfma_f32_16x16x32_bf16(ah[mm][1], bh1, acc, 0, 0, 0);
                acc = __builtin_amdgcn_mfma_f32_16x16x32_bf16(ah[mm][0], bl0, acc, 0, 0, 0);
                acc = __builtin_amdgcn_mfma_f32_16x16x32_bf16(ah[mm][1], bl1, acc, 0, 0, 0);
                acc = __builtin_amdgcn_mfma_f32_16x16x32_bf16(al[mm][0], bh0, acc, 0, 0, 0);
                acc = __builtin_amdgcn_mfma_f32_16x16x32_bf16(al[mm][1], bh1, acc, 0, 0, 0);
#pragma unroll
                for (int s = 0; s < 4; ++s) {
                    float sv = acc[s];
                    int r = mm * 4 + s;
                    bool gt = sv > s1[r];
                    i1[r] = gt ? p : i1[r];
                    s2[r] = fmaxf(s2[r], fminf(s1[r], sv));
                    s1[r] = fmaxf(s1[r], sv);
                }
            }
        }
    }
#pragma unroll
    for (int r = 0; r < 8; ++r) {
        float a1v = s1[r], a2v = s2[r]; int ai = i1[r];
#pragma unroll
        for (int m = 1; m <= 8; m <<= 1) {
            float b1 = __shfl_xor(a1v, m); int bi = __shfl_xor(ai, m);
            float b2 = __shfl_xor(a2v, m);
            float n1 = fmaxf(a1v, b1);
            a2v = fmaxf(fminf(a1v, b1), fmaxf(a2v, b2));
            ai = (b1 > a1v) ? bi : ai;
            a1v = n1;
        }
        if (col == 0) {
            int row = wrow + (r >> 2) * 16 + quad * 4 + (r & 3);
            d12[ph * N + row] = make_float4(a1v, a2v, __int_as_float(ai), 0.f);
        }
    }
}

// ---------------- K3m: merge the four P-parts, write idx, flag near-ties ----------
__global__ __launch_bounds__(256) void k3m_merge(
    const float4* __restrict__ d12, int* __restrict__ idx_ws, float* __restrict__ idx_out,
    int* __restrict__ qn, int* __restrict__ qlist) {
    int row = blockIdx.x * 256 + threadIdx.x;
    float4 a = d12[row];
    float m1 = a.x, m2 = a.y; int i1 = __float_as_int(a.z);
#pragma unroll
    for (int ph = 1; ph < 4; ++ph) {
        float4 b = d12[ph * N + row];
        m2 = fmaxf(fminf(m1, b.x), fmaxf(m2, b.y));
        if (b.x > m1) { i1 = __float_as_int(b.z); m1 = b.x; }
    }
    idx_ws[row] = i1;
    idx_out[row] = (float)i1;
    if (m1 - m2 < 0.5f * TAU + 2e-6f) {
        int qi = atomicAdd(qn, 1);
        qlist[qi] = row;
    }
}

// ---------------- K3r: exact fp32 full-row argmin for flagged rows ----------------
__global__ __launch_bounds__(256) void k3_recheck(
    const float* __restrict__ zqT, const float* __restrict__ cnT,
    const float* __restrict__ cc, const int* __restrict__ qn,
    const int* __restrict__ qlist, int* __restrict__ idx_ws, float* __restrict__ idx_out) {
    __shared__ float zrow[64];
    __shared__ float bv[4];
    __shared__ int   bi4[4];
    int tid = threadIdx.x, w = tid >> 6, lane = tid & 63;
    int nq = qn[0];
    for (int e = blockIdx.x; e < nq; e += gridDim.x) {
        int row = qlist[e];
        __syncthreads();
        if (tid < 64) zrow[tid] = zqT[(size_t)tid * N + row];
        __syncthreads();
        float best = 3.4e38f; int bp = 0;
        for (int pb = w * 2048; pb < (w + 1) * 2048; pb += 64) {
            int p = pb + lane;
            float a0 = 0.f, a1 = 0.f, a2 = 0.f, a3 = 0.f;
#pragma unroll
            for (int k = 0; k < 64; k += 4) {
                a0 = fmaf(zrow[k + 0], cnT[(size_t)(k + 0) * P + p], a0);
                a1 = fmaf(zrow[k + 1], cnT[(size_t)(k + 1) * P + p], a1);
                a2 = fmaf(zrow[k + 2], cnT[(size_t)(k + 2) * P + p], a2);
                a3 = fmaf(zrow[k + 3], cnT[(size_t)(k + 3) * P + p], a3);
            }
            float d = fmaf((a0 + a1) + (a2 + a3), -2.0f, cc[p]);
            if (d < best) { best = d; bp = p; }
        }
#pragma unroll
        for (int m = 1; m < 64; m <<= 1) {
            float ob = __shfl_xor(best, m); int op = __shfl_xor(bp, m);
            if (ob < best || (ob == best && op < bp)) { best = ob; bp = op; }
        }
        if (lane == 0) { bv[w] = best; bi4[w] = bp; }
        __syncthreads();
        if (tid == 0) {
            float b = bv[0]; int pi = bi4[0];
#pragma unroll
            for (int ww = 1; ww < 4; ++ww)
                if (bv[ww] < b || (bv[ww] == b && bi4[ww] < pi)) { b = bv[ww]; pi = bi4[ww]; }
            idx_ws[row] = pi; idx_out[row] = (float)pi;
        }
    }
}

// ---------------- K3b: fused gather + loss (no codesT materialization) ----------
// loss = sum over [C][N] of (zqT[k][r] - cnT[k][idx[r]])^2
__global__ __launch_bounds__(256) void k3b_gather_loss(
    const float* __restrict__ cnT, const int* __restrict__ idx,
    const float* __restrict__ zqT, float* __restrict__ acc) {
    float s = 0.f;
    for (size_t i = (size_t)blockIdx.x * 256 + threadIdx.x; i < (size_t)C * N;
         i += (size_t)gridDim.x * 256) {
        int k = (int)(i >> 15);          // N = 2^15
        int r = (int)(i & (N - 1));
        float d = zqT[i] - cnT[(size_t)k * P + idx[r]];
        s = fmaf(d, d, s);
    }
#pragma unroll
    for (int off = 32; off > 0; off >>= 1) s += __shfl_xor(s, off);
    __shared__ float wsum[4];
    int lane = threadIdx.x & 63, wv = threadIdx.x >> 6;
    if (lane == 0) wsum[wv] = s;
    __syncthreads();
    if (threadIdx.x == 0) atomicAdd(acc, wsum[0] + wsum[1] + wsum[2] + wsum[3]);
}

// ---------------- K4p: w_out -> bf16 hi/lo [F][C] ----------------
__global__ __launch_bounds__(256) void k4_prep(
    const float* __restrict__ w_out, unsigned short* __restrict__ woh,
    unsigned short* __restrict__ wol) {
    int i = blockIdx.x * 256 + threadIdx.x;   // F*C = 49152
    float v = w_out[i];
    unsigned short h = f2bf(v);
    woh[i] = h;
    wol[i] = f2bf(v - bf2f(h));
}

// ---------------- K4: out = codes @ w_out^T + b_out, split-bf16 MFMA ----------------
// codes gathered directly from cnh/cnl by idx (A-frag), w_out from woh/wol (B-frag).
// out error ~2e-6 << 4.9e-4 tol; idx/loss unaffected (use fp32 paths).
// block 256 = 4 waves x 16 rows = 64 rows; f-quarter 192 -> grid 512*4 = 2048 (8/CU)
__global__ __launch_bounds__(256) void k4_out_mfma(
    const unsigned short* __restrict__ cnh, const unsigned short* __restrict__ cnl,
    const unsigned short* __restrict__ woh, const unsigned short* __restrict__ wol,
    const int* __restrict__ idx, const float* __restrict__ b_out, float* __restrict__ out) {
    int tid = threadIdx.x;
    int w = tid >> 6, lane = tid & 63;
    int col = lane & 15, quad = lane >> 4;
    int rb = (blockIdx.x >> 2) * 64;
    int fb = (blockIdx.x & 3) * 192;
    int wrow = rb + w * 16;

    int pg = idx[wrow + col];            // A[m=col][k]: gather code page for this row
    short8 ah[2], al[2];
#pragma unroll
    for (int kf = 0; kf < 2; ++kf) {
        size_t off = (size_t)pg * 64 + kf * 32 + quad * 8;
        ah[kf] = *(const short8*)&cnh[off];
        al[kf] = *(const short8*)&cnl[off];
    }

    for (int ft = 0; ft < 12; ++ft) {
        int f0 = fb + ft * 16;
        size_t bo = (size_t)(f0 + col) * 64 + quad * 8;   // B[n=col][k]
        short8 bh0 = *(const short8*)&woh[bo];
        short8 bh1 = *(const short8*)&woh[bo + 32];
        short8 bl0 = *(const short8*)&wol[bo];
        short8 bl1 = *(const short8*)&wol[bo + 32];
        f32x4 acc = {0.f, 0.f, 0.f, 0.f};
        acc = __builtin_amdgcn_mfma_f32_16x16x32_bf16(ah[0], bh0, acc, 0, 0, 0);
        acc = __builtin_amdgcn_mfma_f32_16x16x32_bf16(ah[1], bh1, acc, 0, 0, 0);
        acc = __builtin_amdgcn_mfma_f32_16x16x32_bf16(ah[0], bl0, acc, 0, 0, 0);
        acc = __builtin_amdgcn_mfma_f32_16x16x32_bf16(ah[1], bl1, acc, 0, 0, 0);
        acc = __builtin_amdgcn_mfma_f32_16x16x32_bf16(al[0], bh0, acc, 0, 0, 0);
        acc = __builtin_amdgcn_mfma_f32_16x16x32_bf16(al[1], bh1, acc, 0, 0, 0);
        float bv = b_out[f0 + col];
#pragma unroll
        for (int s = 0; s < 4; ++s)
            out[(size_t)(wrow + quad * 4 + s) * F + f0 + col] = acc[s] + bv;
    }
}

// ---------------- K6: finalize loss ----------------
__global__ void k6_finalize(const float* __restrict__ acc, float* __restrict__ loss_out) {
    float m = acc[0] / (float)(C * N);
    loss_out[0] = 0.25f * m + m;   // BETA*mean + mean
}

extern "C" void kernel_launch(void* const* d_in, const int* in_sizes, int n_in,
                              void* d_out, int out_size, void* d_ws, size_t ws_size,
                              hipStream_t stream) {
    const float* z      = (const float*)d_in[0];
    const float* w_in   = (const float*)d_in[1];
    const float* b_in   = (const float*)d_in[2];
    const float* w_out  = (const float*)d_in[3];
    const float* b_out  = (const float*)d_in[4];
    const float* cb     = (const float*)d_in[5];
    float* out = (float*)d_out;
    float* ws  = (float*)d_ws;

    unsigned short* cnh = (unsigned short*)(ws + WS_CNH);
    unsigned short* cnl = (unsigned short*)(ws + WS_CNL);
    unsigned short* zqh = (unsigned short*)(ws + WS_ZQH);
    unsigned short* zql = (unsigned short*)(ws + WS_ZQL);
    unsigned short* woh = (unsigned short*)(ws + WS_WOH);
    unsigned short* wol = (unsigned short*)(ws + WS_WOL);

    hipMemsetAsync(ws + WS_QN, 0, 2 * sizeof(float), stream);   // qn + loss acc
    k1_norm_codebook<<<P / 256, 256, 0, stream>>>(cb, ws + WS_CNT, ws + WS_CC, cnh, cnl);
    k4_prep<<<F * C / 256, 256, 0, stream>>>(w_out, woh, wol);
    k2_project<<<N / 64, 256, 0, stream>>>(z, w_in, b_in, ws + WS_ZQT, zqh, zql);
    k3_argmin_mfma<<<1024, 256, 0, stream>>>(zqh, zql, cnh, cnl, (float4*)(ws + WS_D12));
    k3m_merge<<<N / 256, 256, 0, stream>>>((const float4*)(ws + WS_D12),
                                           (int*)(ws + WS_IDX), out + OUT_IDX_OFF,
                                           (int*)(ws + WS_QN), (int*)(ws + WS_QLIST));
    k3_recheck<<<512, 256, 0, stream>>>(ws + WS_ZQT, ws + WS_CNT, ws + WS_CC,
                                        (const int*)(ws + WS_QN), (const int*)(ws + WS_QLIST),
                                        (int*)(ws + WS_IDX), out + OUT_IDX_OFF);
    k3b_gather_loss<<<2048, 256, 0, stream>>>(ws + WS_CNT, (const int*)(ws + WS_IDX),
                                              ws + WS_ZQT, ws + WS_ACC);
    k4_out_mfma<<<2048, 256, 0, stream>>>(cnh, cnl, woh, wol, (const int*)(ws + WS_IDX),
                                          b_out, out);
    k6_finalize<<<1, 1, 0, stream>>>(ws + WS_ACC, out + OUT_LOSS_OFF);
}

// Round 5
// 529.200 us; speedup vs baseline: 1.3510x; 1.1603x over previous
//
#include <hip/hip_runtime.h>

#define N 32768
#define F 768
#define C 64
#define P 8192
#define TAU 1e-3f

typedef __attribute__((ext_vector_type(8))) short short8;
typedef __attribute__((ext_vector_type(4))) float f32x4;

// ---------------- workspace layout (float offsets) ----------------
#define WS_CNT    0                        // cnT   fp32 [C][P] k-major (recheck+loss gather)
#define WS_CC     (WS_CNT + C*P)           // cc    [P]
#define WS_ZQT    (WS_CC + P)              // zqT   fp32 [C][N] k-major (loss+recheck)
#define WS_CODEST (WS_ZQT + C*N)           // hole: reused for w_in splits
#define WS_WIH    WS_CODEST                // w_in hi bf16 [C][F]
#define WS_WIM    (WS_WIH + (C*F)/2)       // w_in mid bf16 [C][F]
#define WS_WIL    (WS_WIM + (C*F)/2)       // w_in lo bf16 [C][F]
#define WS_IDX    (WS_CODEST + C*N)        // idx   [N] int
#define WS_QN     (WS_IDX + N)             // queue count (int)
#define WS_ACC    (WS_QN + 1)              // loss accumulator
#define WS_QLIST  (WS_ACC + 1)             // queue [N] int
#define WS_CNH    ((WS_QLIST + N + 3) & ~3)  // cn_hi bf16 [P][C] row-major
#define WS_CNL    (WS_CNH + (C*P)/2)       // cn_lo bf16 [P][C]
#define WS_ZQH    (WS_CNL + (C*P)/2)       // zq_hi bf16 [N][C] row-major
#define WS_ZQL    (WS_ZQH + (C*N)/2)       // zq_lo bf16 [N][C]
#define WS_D12    (WS_ZQL + (C*N)/2)       // float4 [4][N]: (s1, s2, i1_bits, pad)
#define WS_WOH    (WS_D12 + 16*N)          // w_out hi bf16 [F][C]
#define WS_WOL    (WS_WOH + (F*C)/2)       // w_out lo bf16 [F][C]
// end ≈ 32.0 MB

#define OUT_LOSS_OFF (N*F)
#define OUT_IDX_OFF  (N*F + 1)

__device__ inline unsigned short f2bf(float x) {   // fp32 -> bf16 RNE
    union { float f; unsigned u; } v; v.f = x;
    unsigned r = v.u + 0x7fffu + ((v.u >> 16) & 1u);
    return (unsigned short)(r >> 16);
}
__device__ inline float bf2f(unsigned short b) {
    union { unsigned u; float f; } v; v.u = ((unsigned)b) << 16;
    return v.f;
}

union U32S8 { unsigned u[4]; short8 s; };

// 8 consecutive fp32 -> 3 bf16 levels (trunc split: exact decomposition,
// residual after 3 levels ~2^-24 relative = fp32 rounding noise)
__device__ inline void split3x8(const float* xp, short8& h, short8& m, short8& l) {
    U32S8 hh, mm, ll;
#pragma unroll
    for (int i = 0; i < 4; ++i) {
        float xa = xp[2 * i], xb = xp[2 * i + 1];
        unsigned ha = __float_as_uint(xa) & 0xffff0000u;
        unsigned hb = __float_as_uint(xb) & 0xffff0000u;
        hh.u[i] = (ha >> 16) | hb;
        float ra = xa - __uint_as_float(ha), rb = xb - __uint_as_float(hb);
        unsigned ma = __float_as_uint(ra) & 0xffff0000u;
        unsigned mb = __float_as_uint(rb) & 0xffff0000u;
        mm.u[i] = (ma >> 16) | mb;
        float sa = ra - __uint_as_float(ma), sb = rb - __uint_as_float(mb);
        ll.u[i] = ((__float_as_uint(sa) & 0xffff0000u) >> 16) |
                  (__float_as_uint(sb) & 0xffff0000u);
    }
    h = hh.s; m = mm.s; l = ll.s;
}

// ---------------- K1: normalize codebook -> cnT [C][P], cc, cn_hi/lo [P][C] ----
__global__ __launch_bounds__(256) void k1_norm_codebook(
    const float* __restrict__ cb, float* __restrict__ cnT, float* __restrict__ cc,
    unsigned short* __restrict__ cnh, unsigned short* __restrict__ cnl) {
    int p = blockIdx.x * 256 + threadIdx.x;   // one thread per page
    const float4* cb4 = (const float4*)(cb + (size_t)p * C);
    float4 v[16];
    float ss = 0.f;
#pragma unroll
    for (int i = 0; i < 16; ++i) {
        v[i] = cb4[i];
        ss += v[i].x * v[i].x + v[i].y * v[i].y + v[i].z * v[i].z + v[i].w * v[i].w;
    }
    float nrm = sqrtf(ss);
    float s2 = 0.f;
    unsigned short hb[64], lb[64];
#pragma unroll
    for (int i = 0; i < 16; ++i) {
        float c4[4] = {v[i].x / nrm, v[i].y / nrm, v[i].z / nrm, v[i].w / nrm};
#pragma unroll
        for (int j = 0; j < 4; ++j) {
            cnT[(size_t)(i * 4 + j) * P + p] = c4[j];
            s2 += c4[j] * c4[j];
            unsigned short h = f2bf(c4[j]);
            hb[i * 4 + j] = h;
            lb[i * 4 + j] = f2bf(c4[j] - bf2f(h));
        }
    }
    cc[p] = s2;
#pragma unroll
    for (int i = 0; i < 8; ++i) {
        uint4 hv, lv;
        hv.x = (unsigned)hb[i*8+0] | ((unsigned)hb[i*8+1] << 16);
        hv.y = (unsigned)hb[i*8+2] | ((unsigned)hb[i*8+3] << 16);
        hv.z = (unsigned)hb[i*8+4] | ((unsigned)hb[i*8+5] << 16);
        hv.w = (unsigned)hb[i*8+6] | ((unsigned)hb[i*8+7] << 16);
        lv.x = (unsigned)lb[i*8+0] | ((unsigned)lb[i*8+1] << 16);
        lv.y = (unsigned)lb[i*8+2] | ((unsigned)lb[i*8+3] << 16);
        lv.z = (unsigned)lb[i*8+4] | ((unsigned)lb[i*8+5] << 16);
        lv.w = (unsigned)lb[i*8+6] | ((unsigned)lb[i*8+7] << 16);
        *(uint4*)&cnh[(size_t)p * 64 + i * 8] = hv;
        *(uint4*)&cnl[(size_t)p * 64 + i * 8] = lv;
    }
}

// ---------------- K2p: w_in -> 3-level bf16 split [C][F] ----------------
__global__ __launch_bounds__(256) void k2_prep(
    const float* __restrict__ w_in, unsigned short* __restrict__ wih,
    unsigned short* __restrict__ wim, unsigned short* __restrict__ wil) {
    int i = blockIdx.x * 256 + threadIdx.x;   // C*F = 49152
    float x = w_in[i];
    unsigned hu = __float_as_uint(x) & 0xffff0000u;
    float r1 = x - __uint_as_float(hu);
    unsigned mu = __float_as_uint(r1) & 0xffff0000u;
    float r2 = r1 - __uint_as_float(mu);
    wih[i] = (unsigned short)(hu >> 16);
    wim[i] = (unsigned short)(mu >> 16);
    wil[i] = f2bf(r2);
}

// ---------------- K2: zq = normalize(z @ w_in^T + b_in), 3x3-split MFMA ----------
// 1 wave/block, 16 rows/wave, grid 2048 (8 blocks/CU). No barriers in K-loop:
// z loaded direct from global (coalesced 32B/lane), split 3-way in registers;
// w from pre-split wih/wim/wil (L2-hot, 288 KB). 6 MFMA products per (kt,nt):
// hh+hm+mh+hl+lh+mm -> dropped terms ~2^-24 rel = fp32-rounding-grade zqT.
__global__ __launch_bounds__(64) void k2_project_mfma(
    const float* __restrict__ z,
    const unsigned short* __restrict__ wih, const unsigned short* __restrict__ wim,
    const unsigned short* __restrict__ wil, const float* __restrict__ b_in,
    float* __restrict__ zqT, unsigned short* __restrict__ zqh,
    unsigned short* __restrict__ zql) {
    __shared__ float lq[16 * 65];
    int lane = threadIdx.x;
    int col = lane & 15, quad = lane >> 4;
    int wrow = blockIdx.x * 16;

    f32x4 acc[4];
#pragma unroll
    for (int nt = 0; nt < 4; ++nt) acc[nt] = (f32x4){0.f, 0.f, 0.f, 0.f};

    const float* zrow = z + (size_t)(wrow + col) * F + quad * 8;
    size_t bbase[4];
#pragma unroll
    for (int nt = 0; nt < 4; ++nt) bbase[nt] = (size_t)(nt * 16 + col) * F + quad * 8;

#pragma unroll 2
    for (int kt = 0; kt < F / 32; ++kt) {
        float xz[8];
        *(float4*)&xz[0] = *(const float4*)&zrow[kt * 32];
        *(float4*)&xz[4] = *(const float4*)&zrow[kt * 32 + 4];
        short8 ah, am, al;
        split3x8(xz, ah, am, al);
#pragma unroll
        for (int nt = 0; nt < 4; ++nt) {
            size_t bo = bbase[nt] + kt * 32;
            short8 bh = *(const short8*)&wih[bo];
            short8 bm = *(const short8*)&wim[bo];
            short8 bl = *(const short8*)&wil[bo];
            acc[nt] = __builtin_amdgcn_mfma_f32_16x16x32_bf16(ah, bh, acc[nt], 0, 0, 0);
            acc[nt] = __builtin_amdgcn_mfma_f32_16x16x32_bf16(ah, bm, acc[nt], 0, 0, 0);
            acc[nt] = __builtin_amdgcn_mfma_f32_16x16x32_bf16(am, bh, acc[nt], 0, 0, 0);
            acc[nt] = __builtin_amdgcn_mfma_f32_16x16x32_bf16(ah, bl, acc[nt], 0, 0, 0);
            acc[nt] = __builtin_amdgcn_mfma_f32_16x16x32_bf16(al, bh, acc[nt], 0, 0, 0);
            acc[nt] = __builtin_amdgcn_mfma_f32_16x16x32_bf16(am, bm, acc[nt], 0, 0, 0);
        }
    }
    // y[row = wrow+quad*4+s][code = nt*16+col] = acc[nt][s] + b_in[code]
    float y[4][4];
#pragma unroll
    for (int nt = 0; nt < 4; ++nt) {
        float bv = b_in[nt * 16 + col];
#pragma unroll
        for (int s = 0; s < 4; ++s) y[nt][s] = acc[nt][s] + bv;
    }
    // row norm: local 4 codes + shfl over the 16 cols (xor 1,2,4,8 stays in-quad)
#pragma unroll
    for (int s = 0; s < 4; ++s) {
        float ssum = 0.f;
#pragma unroll
        for (int nt = 0; nt < 4; ++nt) ssum += y[nt][s] * y[nt][s];
#pragma unroll
        for (int m = 1; m <= 8; m <<= 1) ssum += __shfl_xor(ssum, m);
        float nrm = sqrtf(ssum);
#pragma unroll
        for (int nt = 0; nt < 4; ++nt) y[nt][s] /= nrm;
    }
    // transpose via LDS (wave-private; compiler orders ds ops via lgkmcnt)
#pragma unroll
    for (int nt = 0; nt < 4; ++nt)
#pragma unroll
        for (int s = 0; s < 4; ++s)
            lq[(quad * 4 + s) * 65 + nt * 16 + col] = y[nt][s];
    __syncthreads();
    // pack zqh/zql: 4 lanes per row, 16 codes per lane
    {
        int r = lane >> 2, part = lane & 3;
        float v[16];
#pragma unroll
        for (int t = 0; t < 16; ++t) v[t] = lq[r * 65 + part * 16 + t];
        unsigned hu[8], lu[8];
#pragma unroll
        for (int k = 0; k < 8; ++k) {
            unsigned short h0 = f2bf(v[2 * k]), h1 = f2bf(v[2 * k + 1]);
            unsigned short l0 = f2bf(v[2 * k] - bf2f(h0));
            unsigned short l1 = f2bf(v[2 * k + 1] - bf2f(h1));
            hu[k] = (unsigned)h0 | ((unsigned)h1 << 16);
            lu[k] = (unsigned)l0 | ((unsigned)l1 << 16);
        }
        size_t ro = (size_t)(wrow + r) * 64 + part * 16;
        *(uint4*)&zqh[ro] = make_uint4(hu[0], hu[1], hu[2], hu[3]);
        *(uint4*)&zqh[ro + 8] = make_uint4(hu[4], hu[5], hu[6], hu[7]);
        *(uint4*)&zql[ro] = make_uint4(lu[0], lu[1], lu[2], lu[3]);
        *(uint4*)&zql[ro + 8] = make_uint4(lu[4], lu[5], lu[6], lu[7]);
    }
    // zqT: lane = code, 16 rows contiguous -> 4x float4 stores
    {
        float t[16];
#pragma unroll
        for (int r = 0; r < 16; ++r) t[r] = lq[r * 65 + lane];
        float* dst = &zqT[(size_t)lane * N + wrow];
#pragma unroll
        for (int g = 0; g < 4; ++g)
            *(float4*)&dst[g * 4] = make_float4(t[4 * g], t[4 * g + 1], t[4 * g + 2], t[4 * g + 3]);
    }
}

// ---------------- K3: split-bf16 MFMA similarity + top-2, 32 rows/wave ----------------
__global__ __launch_bounds__(256, 4) void k3_argmin_mfma(
    const unsigned short* __restrict__ zqh, const unsigned short* __restrict__ zql,
    const unsigned short* __restrict__ cnh, const unsigned short* __restrict__ cnl,
    float4* __restrict__ d12) {
    __shared__ unsigned short lfrag[8 * 4 * 64 * 8];   // [nt][f][slot][8] = 32 KB
    int tid = threadIdx.x;
    int w = tid >> 6, lane = tid & 63;
    int col = lane & 15, quad = lane >> 4;
    int rb = (blockIdx.x & 255) * 128;
    int ph = blockIdx.x >> 8;            // which quarter of P
    int wrow = rb + w * 32;              // wave: rows [wrow, wrow+32)
    int p0 = ph * (P / 4);

    short8 ah[2][2], al[2][2];
#pragma unroll
    for (int mm = 0; mm < 2; ++mm)
#pragma unroll
        for (int kf = 0; kf < 2; ++kf) {
            size_t off = (size_t)(wrow + mm * 16 + col) * 64 + kf * 32 + quad * 8;
            ah[mm][kf] = *(const short8*)&zqh[off];
            al[mm][kf] = *(const short8*)&zql[off];
        }

    float s1[8], s2[8]; int i1[8];
#pragma unroll
    for (int r = 0; r < 8; ++r) { s1[r] = -3.4e38f; s2[r] = -3.4e38f; i1[r] = 0; }

    int sq = (tid >> 4) & 3, scol = tid & 15, sf = w;
    const unsigned short* ssrc = (sf & 2) ? cnl : cnh;
    int skf = sf & 1;

    for (int pt = p0; pt < p0 + P / 4; pt += 128) {
        __syncthreads();
#pragma unroll
        for (int nt = 0; nt < 8; ++nt) {
            int p = pt + nt * 16 + scol;
            uint4 dv = *(const uint4*)&ssrc[(size_t)p * 64 + skf * 32 + sq * 8];
            *(uint4*)&lfrag[((nt * 4 + sf) * 64 + (tid & 63)) * 8] = dv;
        }
        __syncthreads();
#pragma unroll 2
        for (int nt = 0; nt < 8; ++nt) {
            short8 bh0 = *(const short8*)&lfrag[((nt * 4 + 0) * 64 + lane) * 8];
            short8 bh1 = *(const short8*)&lfrag[((nt * 4 + 1) * 64 + lane) * 8];
            short8 bl0 = *(const short8*)&lfrag[((nt * 4 + 2) * 64 + lane) * 8];
            short8 bl1 = *(const short8*)&lfrag[((nt * 4 + 3) * 64 + lane) * 8];
            int p = pt + nt * 16 + col;
#pragma unroll
            for (int mm = 0; mm < 2; ++mm) {
                f32x4 acc = {0.f, 0.f, 0.f, 0.f};
                acc = __builtin_amdgcn_mfma_f32_16x16x32_bf16(ah[mm][0], bh0, acc, 0, 0, 0);
                acc = __builtin_amdgcn_mfma_f32_16x16x32_bf16(ah[mm][1], bh1, acc, 0, 0, 0);
                acc = __builtin_amdgcn_mfma_f32_16x16x32_bf16(ah[mm][0], bl0, acc, 0, 0, 0);
                acc = __builtin_amdgcn_mfma_f32_16x16x32_bf16(ah[mm][1], bl1, acc, 0, 0, 0);
                acc = __builtin_amdgcn_mfma_f32_16x16x32_bf16(al[mm][0], bh0, acc, 0, 0, 0);
                acc = __builtin_amdgcn_mfma_f32_16x16x32_bf16(al[mm][1], bh1, acc, 0, 0, 0);
#pragma unroll
                for (int s = 0; s < 4; ++s) {
                    float sv = acc[s];
                    int r = mm * 4 + s;
                    bool gt = sv > s1[r];
                    i1[r] = gt ? p : i1[r];
                    s2[r] = fmaxf(s2[r], fminf(s1[r], sv));
                    s1[r] = fmaxf(s1[r], sv);
                }
            }
        }
    }
#pragma unroll
    for (int r = 0; r < 8; ++r) {
        float a1v = s1[r], a2v = s2[r]; int ai = i1[r];
#pragma unroll
        for (int m = 1; m <= 8; m <<= 1) {
            float b1 = __shfl_xor(a1v, m); int bi = __shfl_xor(ai, m);
            float b2 = __shfl_xor(a2v, m);
            float n1 = fmaxf(a1v, b1);
            a2v = fmaxf(fminf(a1v, b1), fmaxf(a2v, b2));
            ai = (b1 > a1v) ? bi : ai;
            a1v = n1;
        }
        if (col == 0) {
            int row = wrow + (r >> 2) * 16 + quad * 4 + (r & 3);
            d12[ph * N + row] = make_float4(a1v, a2v, __int_as_float(ai), 0.f);
        }
    }
}

// ---------------- K3m: merge the four P-parts, write idx, flag near-ties ----------
__global__ __launch_bounds__(256) void k3m_merge(
    const float4* __restrict__ d12, int* __restrict__ idx_ws, float* __restrict__ idx_out,
    int* __restrict__ qn, int* __restrict__ qlist) {
    int row = blockIdx.x * 256 + threadIdx.x;
    float4 a = d12[row];
    float m1 = a.x, m2 = a.y; int i1 = __float_as_int(a.z);
#pragma unroll
    for (int ph = 1; ph < 4; ++ph) {
        float4 b = d12[ph * N + row];
        m2 = fmaxf(fminf(m1, b.x), fmaxf(m2, b.y));
        if (b.x > m1) { i1 = __float_as_int(b.z); m1 = b.x; }
    }
    idx_ws[row] = i1;
    idx_out[row] = (float)i1;
    if (m1 - m2 < 0.5f * TAU + 2e-6f) {
        int qi = atomicAdd(qn, 1);
        qlist[qi] = row;
    }
}

// ---------------- K3r: exact fp32 full-row argmin for flagged rows ----------------
__global__ __launch_bounds__(256) void k3_recheck(
    const float* __restrict__ zqT, const float* __restrict__ cnT,
    const float* __restrict__ cc, const int* __restrict__ qn,
    const int* __restrict__ qlist, int* __restrict__ idx_ws, float* __restrict__ idx_out) {
    __shared__ float zrow[64];
    __shared__ float bv[4];
    __shared__ int   bi4[4];
    int tid = threadIdx.x, w = tid >> 6, lane = tid & 63;
    int nq = qn[0];
    for (int e = blockIdx.x; e < nq; e += gridDim.x) {
        int row = qlist[e];
        __syncthreads();
        if (tid < 64) zrow[tid] = zqT[(size_t)tid * N + row];
        __syncthreads();
        float best = 3.4e38f; int bp = 0;
        for (int pb = w * 2048; pb < (w + 1) * 2048; pb += 64) {
            int p = pb + lane;
            float a0 = 0.f, a1 = 0.f, a2 = 0.f, a3 = 0.f;
#pragma unroll
            for (int k = 0; k < 64; k += 4) {
                a0 = fmaf(zrow[k + 0], cnT[(size_t)(k + 0) * P + p], a0);
                a1 = fmaf(zrow[k + 1], cnT[(size_t)(k + 1) * P + p], a1);
                a2 = fmaf(zrow[k + 2], cnT[(size_t)(k + 2) * P + p], a2);
                a3 = fmaf(zrow[k + 3], cnT[(size_t)(k + 3) * P + p], a3);
            }
            float d = fmaf((a0 + a1) + (a2 + a3), -2.0f, cc[p]);
            if (d < best) { best = d; bp = p; }
        }
#pragma unroll
        for (int m = 1; m < 64; m <<= 1) {
            float ob = __shfl_xor(best, m); int op = __shfl_xor(bp, m);
            if (ob < best || (ob == best && op < bp)) { best = ob; bp = op; }
        }
        if (lane == 0) { bv[w] = best; bi4[w] = bp; }
        __syncthreads();
        if (tid == 0) {
            float b = bv[0]; int pi = bi4[0];
#pragma unroll
            for (int ww = 1; ww < 4; ++ww)
                if (bv[ww] < b || (bv[ww] == b && bi4[ww] < pi)) { b = bv[ww]; pi = bi4[ww]; }
            idx_ws[row] = pi; idx_out[row] = (float)pi;
        }
    }
}

// ---------------- K3b: fused gather + loss (no codesT materialization) ----------
__global__ __launch_bounds__(256) void k3b_gather_loss(
    const float* __restrict__ cnT, const int* __restrict__ idx,
    const float* __restrict__ zqT, float* __restrict__ acc) {
    float s = 0.f;
    for (size_t i = (size_t)blockIdx.x * 256 + threadIdx.x; i < (size_t)C * N;
         i += (size_t)gridDim.x * 256) {
        int k = (int)(i >> 15);          // N = 2^15
        int r = (int)(i & (N - 1));
        float d = zqT[i] - cnT[(size_t)k * P + idx[r]];
        s = fmaf(d, d, s);
    }
#pragma unroll
    for (int off = 32; off > 0; off >>= 1) s += __shfl_xor(s, off);
    __shared__ float wsum[4];
    int lane = threadIdx.x & 63, wv = threadIdx.x >> 6;
    if (lane == 0) wsum[wv] = s;
    __syncthreads();
    if (threadIdx.x == 0) atomicAdd(acc, wsum[0] + wsum[1] + wsum[2] + wsum[3]);
}

// ---------------- K4p: w_out -> bf16 hi/lo [F][C] ----------------
__global__ __launch_bounds__(256) void k4_prep(
    const float* __restrict__ w_out, unsigned short* __restrict__ woh,
    unsigned short* __restrict__ wol) {
    int i = blockIdx.x * 256 + threadIdx.x;   // F*C = 49152
    float v = w_out[i];
    unsigned short h = f2bf(v);
    woh[i] = h;
    wol[i] = f2bf(v - bf2f(h));
}

// ---------------- K4: out = codes @ w_out^T + b_out, split-bf16 MFMA ----------------
__global__ __launch_bounds__(256) void k4_out_mfma(
    const unsigned short* __restrict__ cnh, const unsigned short* __restrict__ cnl,
    const unsigned short* __restrict__ woh, const unsigned short* __restrict__ wol,
    const int* __restrict__ idx, const float* __restrict__ b_out, float* __restrict__ out) {
    int tid = threadIdx.x;
    int w = tid >> 6, lane = tid & 63;
    int col = lane & 15, quad = lane >> 4;
    int rb = (blockIdx.x >> 2) * 64;
    int fb = (blockIdx.x & 3) * 192;
    int wrow = rb + w * 16;

    int pg = idx[wrow + col];            // A[m=col][k]: gather code page for this row
    short8 ah[2], al[2];
#pragma unroll
    for (int kf = 0; kf < 2; ++kf) {
        size_t off = (size_t)pg * 64 + kf * 32 + quad * 8;
        ah[kf] = *(const short8*)&cnh[off];
        al[kf] = *(const short8*)&cnl[off];
    }

    for (int ft = 0; ft < 12; ++ft) {
        int f0 = fb + ft * 16;
        size_t bo = (size_t)(f0 + col) * 64 + quad * 8;   // B[n=col][k]
        short8 bh0 = *(const short8*)&woh[bo];
        short8 bh1 = *(const short8*)&woh[bo + 32];
        short8 bl0 = *(const short8*)&wol[bo];
        short8 bl1 = *(const short8*)&wol[bo + 32];
        f32x4 acc = {0.f, 0.f, 0.f, 0.f};
        acc = __builtin_amdgcn_mfma_f32_16x16x32_bf16(ah[0], bh0, acc, 0, 0, 0);
        acc = __builtin_amdgcn_mfma_f32_16x16x32_bf16(ah[1], bh1, acc, 0, 0, 0);
        acc = __builtin_amdgcn_mfma_f32_16x16x32_bf16(ah[0], bl0, acc, 0, 0, 0);
        acc = __builtin_amdgcn_mfma_f32_16x16x32_bf16(ah[1], bl1, acc, 0, 0, 0);
        acc = __builtin_amdgcn_mfma_f32_16x16x32_bf16(al[0], bh0, acc, 0, 0, 0);
        acc = __builtin_amdgcn_mfma_f32_16x16x32_bf16(al[1], bh1, acc, 0, 0, 0);
        float bv = b_out[f0 + col];
#pragma unroll
        for (int s = 0; s < 4; ++s)
            out[(size_t)(wrow + quad * 4 + s) * F + f0 + col] = acc[s] + bv;
    }
}

// ---------------- K6: finalize loss ----------------
__global__ void k6_finalize(const float* __restrict__ acc, float* __restrict__ loss_out) {
    float m = acc[0] / (float)(C * N);
    loss_out[0] = 0.25f * m + m;   // BETA*mean + mean
}

extern "C" void kernel_launch(void* const* d_in, const int* in_sizes, int n_in,
                              void* d_out, int out_size, void* d_ws, size_t ws_size,
                              hipStream_t stream) {
    const float* z      = (const float*)d_in[0];
    const float* w_in   = (const float*)d_in[1];
    const float* b_in   = (const float*)d_in[2];
    const float* w_out  = (const float*)d_in[3];
    const float* b_out  = (const float*)d_in[4];
    const float* cb     = (const float*)d_in[5];
    float* out = (float*)d_out;
    float* ws  = (float*)d_ws;

    unsigned short* cnh = (unsigned short*)(ws + WS_CNH);
    unsigned short* cnl = (unsigned short*)(ws + WS_CNL);
    unsigned short* zqh = (unsigned short*)(ws + WS_ZQH);
    unsigned short* zql = (unsigned short*)(ws + WS_ZQL);
    unsigned short* woh = (unsigned short*)(ws + WS_WOH);
    unsigned short* wol = (unsigned short*)(ws + WS_WOL);
    unsigned short* wih = (unsigned short*)(ws + WS_WIH);
    unsigned short* wim = (unsigned short*)(ws + WS_WIM);
    unsigned short* wil = (unsigned short*)(ws + WS_WIL);

    hipMemsetAsync(ws + WS_QN, 0, 2 * sizeof(float), stream);   // qn + loss acc
    k1_norm_codebook<<<P / 256, 256, 0, stream>>>(cb, ws + WS_CNT, ws + WS_CC, cnh, cnl);
    k2_prep<<<C * F / 256, 256, 0, stream>>>(w_in, wih, wim, wil);
    k4_prep<<<F * C / 256, 256, 0, stream>>>(w_out, woh, wol);
    k2_project_mfma<<<N / 16, 64, 0, stream>>>(z, wih, wim, wil, b_in,
                                               ws + WS_ZQT, zqh, zql);
    k3_argmin_mfma<<<1024, 256, 0, stream>>>(zqh, zql, cnh, cnl, (float4*)(ws + WS_D12));
    k3m_merge<<<N / 256, 256, 0, stream>>>((const float4*)(ws + WS_D12),
                                           (int*)(ws + WS_IDX), out + OUT_IDX_OFF,
                                           (int*)(ws + WS_QN), (int*)(ws + WS_QLIST));
    k3_recheck<<<512, 256, 0, stream>>>(ws + WS_ZQT, ws + WS_CNT, ws + WS_CC,
                                        (const int*)(ws + WS_QN), (const int*)(ws + WS_QLIST),
                                        (int*)(ws + WS_IDX), out + OUT_IDX_OFF);
    k3b_gather_loss<<<2048, 256, 0, stream>>>(ws + WS_CNT, (const int*)(ws + WS_IDX),
                                              ws + WS_ZQT, ws + WS_ACC);
    k4_out_mfma<<<2048, 256, 0, stream>>>(cnh, cnl, woh, wol, (const int*)(ws + WS_IDX),
                                          b_out, out);
    k6_finalize<<<1, 1, 0, stream>>>(ws + WS_ACC, out + OUT_LOSS_OFF);
}